// Round 1
// baseline (561.900 us; speedup 1.0000x reference)
//
#include <hip/hip_runtime.h>

// Problem constants
#define NB 16
#define NS 512
#define ND 2048
#define NH 16
#define NG 4
#define NHD 128
#define NM (NB * NS)      // 8192 rows (b*s)
#define NKD (NG * NHD)    // 512
#define HEAD_SCALE 0.08838834764831845f

typedef _Float16 h8 __attribute__((ext_vector_type(8)));
typedef float fx4 __attribute__((ext_vector_type(4)));

// global -> LDS direct copy, 16B per lane. LDS dest must be wave-uniform base;
// HW adds lane*16. Integer round-trip for addrspace casts (low 32 bits == LDS offset).
__device__ __forceinline__ void gload16(const void* g, void* l) {
  __builtin_amdgcn_global_load_lds(
      (__attribute__((address_space(1))) void*)(unsigned long long)g,
      (__attribute__((address_space(3))) void*)(unsigned long long)l,
      16, 0, 0);
}

// ---------------- prep kernels ----------------

__global__ void cvt_x_kernel(const float* __restrict__ in, _Float16* __restrict__ out, int n8) {
  int i = blockIdx.x * 256 + threadIdx.x;
  if (i >= n8) return;
  const fx4* p = (const fx4*)in;
  fx4 a = p[2 * i], b = p[2 * i + 1];
  h8 h;
  h[0] = (_Float16)a[0]; h[1] = (_Float16)a[1]; h[2] = (_Float16)a[2]; h[3] = (_Float16)a[3];
  h[4] = (_Float16)b[0]; h[5] = (_Float16)b[1]; h[6] = (_Float16)b[2]; h[7] = (_Float16)b[3];
  ((h8*)out)[i] = h;
}

// w[K][N] f32 -> wt[N][K] f16 (64x64 LDS tile transpose)
__global__ void wtrans_kernel(const float* __restrict__ w, _Float16* __restrict__ wt, int K, int N) {
  __shared__ float t[64][65];
  int n0 = blockIdx.x * 64, k0 = blockIdx.y * 64;
#pragma unroll
  for (int it = 0; it < 16; ++it) {
    int idx = it * 256 + threadIdx.x;
    int r = idx >> 6, c = idx & 63;
    t[r][c] = w[(size_t)(k0 + r) * N + n0 + c];
  }
  __syncthreads();
#pragma unroll
  for (int it = 0; it < 16; ++it) {
    int idx = it * 256 + threadIdx.x;
    int r = idx >> 6, c = idx & 63;
    wt[(size_t)(n0 + r) * K + k0 + c] = (_Float16)t[c][r];
  }
}

__global__ void rope_tables_kernel(float* __restrict__ cosT, float* __restrict__ sinT) {
  int i = blockIdx.x * 256 + threadIdx.x;  // 512*64 total
  int s = i >> 6, f = i & 63;
  // inv_freq = 10000^(-f/64) = 2^(-f/64 * log2(10000))
  float inv = exp2f(-(float)f * (13.287712379549449f / 64.0f));
  float a = (float)s * inv;
  cosT[i] = cosf(a);
  sinT[i] = sinf(a);
}

// per (row, head): RMSNorm over 128, RoPE, *outScale, in-place f16
__global__ void norm_rope_kernel(_Float16* __restrict__ X, const float* __restrict__ scale,
                                 const float* __restrict__ cosT, const float* __restrict__ sinT,
                                 int hshift, int rowStride, float outScale) {
  int wid = threadIdx.x >> 6, lane = threadIdx.x & 63;
  int task = blockIdx.x * 4 + wid;
  int row = task >> hshift;
  int head = task & ((1 << hshift) - 1);
  _Float16* p = X + (size_t)row * rowStride + head * NHD;
  float x1 = (float)p[lane], x2 = (float)p[lane + 64];
  float ss = x1 * x1 + x2 * x2;
#pragma unroll
  for (int m = 1; m < 64; m <<= 1) ss += __shfl_xor(ss, m, 64);
  float rn = rsqrtf(ss * (1.0f / 128.0f) + 1e-6f);
  int s = row & (NS - 1);
  float c = cosT[s * 64 + lane], sn = sinT[s * 64 + lane];
  float n1 = x1 * rn * scale[lane], n2 = x2 * rn * scale[64 + lane];
  p[lane] = (_Float16)((n1 * c - n2 * sn) * outScale);
  p[lane + 64] = (_Float16)((n1 * sn + n2 * c) * outScale);
}

// ---------------- GEMM: C[M][N] = A[M][K](f16) * Bt[N][K]^T + bias ----------------

__device__ __forceinline__ void st_out(float* p, float v) { *p = v; }
__device__ __forceinline__ void st_out(_Float16* p, float v) { *p = (_Float16)v; }

template <typename OT>
__global__ __launch_bounds__(256, 3) void gemm_bt_kernel(
    const _Float16* __restrict__ A, const _Float16* __restrict__ Bt,
    const float* __restrict__ bias, OT* __restrict__ C, int N, int K) {
  __shared__ alignas(16) _Float16 As[128 * 64];
  __shared__ alignas(16) _Float16 Bs[128 * 64];
  const int tid = threadIdx.x;
  const int lane = tid & 63, wid = tid >> 6;
  const int wr = wid >> 1, wc = wid & 1;
  const int la = lane & 15, lb = (lane >> 4) * 8;
  const int bm = blockIdx.y * 128, bn = blockIdx.x * 128;

  fx4 acc[4][4] = {};

  for (int kt = 0; kt < K; kt += 64) {
    const _Float16* Ag = A + (size_t)bm * K + kt;
    const _Float16* Bg = Bt + (size_t)bn * K + kt;
#pragma unroll
    for (int it = 0; it < 4; ++it) {
      int cb = it * 256 + wid * 64;  // wave-uniform chunk base
      int ca = cb + lane;
      int r = ca >> 3, cc = ca & 7;  // 8 chunks of 16B per 64-f16 row
      gload16(Ag + (size_t)r * K + cc * 8, &As[cb * 8]);
      gload16(Bg + (size_t)r * K + cc * 8, &Bs[cb * 8]);
    }
    __syncthreads();
#pragma unroll
    for (int kk = 0; kk < 2; ++kk) {
      h8 af[4], bf[4];
#pragma unroll
      for (int m = 0; m < 4; ++m)
        af[m] = *(const h8*)&As[(wr * 64 + m * 16 + la) * 64 + kk * 32 + lb];
#pragma unroll
      for (int n = 0; n < 4; ++n)
        bf[n] = *(const h8*)&Bs[(wc * 64 + n * 16 + la) * 64 + kk * 32 + lb];
#pragma unroll
      for (int m = 0; m < 4; ++m)
#pragma unroll
        for (int n = 0; n < 4; ++n)
          acc[m][n] = __builtin_amdgcn_mfma_f32_16x16x32_f16(af[m], bf[n], acc[m][n], 0, 0, 0);
    }
    __syncthreads();
  }
#pragma unroll
  for (int m = 0; m < 4; ++m) {
    int row0 = bm + wr * 64 + m * 16 + (lane >> 4) * 4;
#pragma unroll
    for (int n = 0; n < 4; ++n) {
      int col = bn + wc * 64 + n * 16 + la;
      float bvv = bias[col];
#pragma unroll
      for (int r = 0; r < 4; ++r)
        st_out(&C[(size_t)(row0 + r) * N + col], acc[m][n][r] + bvv);
    }
  }
}

// ---------------- flash attention ----------------
// grid (S/64, NH, NB); 4 waves, each owns 16 q-rows. Q pre-scaled by HEAD_SCALE;
// logits get another *HEAD_SCALE (reference applies it twice).

__global__ __launch_bounds__(256, 2) void attn_kernel(
    const _Float16* __restrict__ Q, const _Float16* __restrict__ Kb,
    const _Float16* __restrict__ Vb, _Float16* __restrict__ ctx) {
  const int qt = blockIdx.x, h = blockIdx.y, b = blockIdx.z;
  const int g = h >> 2;
  const int lane = threadIdx.x & 63, w = threadIdx.x >> 6;
  const int la = lane & 15, lb = (lane >> 4) * 8;
  __shared__ alignas(16) _Float16 Ks[64 * 128];
  __shared__ alignas(16) _Float16 Vt[128 * 72];   // padded V^T
  __shared__ alignas(16) _Float16 Ps[4][16 * 72]; // per-wave P, padded

  h8 qf[4];
  {
    const _Float16* Qg = Q + ((size_t)(b * NS + qt * 64 + w * 16 + la)) * ND + h * NHD + lb;
#pragma unroll
    for (int kc = 0; kc < 4; ++kc) qf[kc] = *(const h8*)(Qg + kc * 32);
  }

  float mrun[4], lrun[4];
  fx4 oacc[8] = {};
#pragma unroll
  for (int r = 0; r < 4; ++r) { mrun[r] = -1e30f; lrun[r] = 0.f; }

  const int qrow0 = qt * 64 + w * 16 + (lane >> 4) * 4;

  for (int kt = 0; kt <= qt; ++kt) {
    const _Float16* Kg = Kb + ((size_t)(b * NS + kt * 64)) * NKD + g * NHD;
    const _Float16* Vg = Vb + ((size_t)(b * NS + kt * 64)) * NKD + g * NHD;
#pragma unroll
    for (int it = 0; it < 4; ++it) {
      int cb = it * 256 + w * 64;
      int ca = cb + lane;
      int rr = ca >> 4, hc = ca & 15;
      gload16(Kg + (size_t)rr * NKD + hc * 8, &Ks[cb * 8]);
    }
#pragma unroll
    for (int it = 0; it < 4; ++it) {  // V staged transposed via regs
      int ca = it * 256 + threadIdx.x;
      int kv = ca >> 4, hc = ca & 15;
      h8 v = *(const h8*)(Vg + (size_t)kv * NKD + hc * 8);
#pragma unroll
      for (int e = 0; e < 8; ++e) Vt[(hc * 8 + e) * 72 + kv] = v[e];
    }
    __syncthreads();

    // QK^T: 16 q-rows x 64 kv
    fx4 sc[4] = {};
#pragma unroll
    for (int n = 0; n < 4; ++n) {
#pragma unroll
      for (int kc = 0; kc < 4; ++kc) {
        h8 bk = *(const h8*)&Ks[(n * 16 + la) * 128 + kc * 32 + lb];
        sc[n] = __builtin_amdgcn_mfma_f32_16x16x32_f16(qf[kc], bk, sc[n], 0, 0, 0);
      }
    }

    float pv[4][4];
    float rm[4] = {-1e30f, -1e30f, -1e30f, -1e30f};
#pragma unroll
    for (int n = 0; n < 4; ++n) {
      int kv = kt * 64 + n * 16 + la;
#pragma unroll
      for (int r = 0; r < 4; ++r) {
        float sv = sc[n][r] * HEAD_SCALE;
        sv = (kv > qrow0 + r) ? -1e30f : sv;
        pv[n][r] = sv;
        rm[r] = fmaxf(rm[r], sv);
      }
    }
#pragma unroll
    for (int r = 0; r < 4; ++r) {
#pragma unroll
      for (int m = 1; m < 16; m <<= 1) rm[r] = fmaxf(rm[r], __shfl_xor(rm[r], m, 64));
      float mn = fmaxf(mrun[r], rm[r]);
      float corr = __expf(mrun[r] - mn);
      mrun[r] = mn;
      lrun[r] *= corr;
#pragma unroll
      for (int f = 0; f < 8; ++f) oacc[f][r] *= corr;
    }
    float rs[4] = {0.f, 0.f, 0.f, 0.f};
#pragma unroll
    for (int n = 0; n < 4; ++n)
#pragma unroll
      for (int r = 0; r < 4; ++r) {
        float e = __expf(pv[n][r] - mrun[r]);
        pv[n][r] = e;
        rs[r] += e;
      }
#pragma unroll
    for (int r = 0; r < 4; ++r) {
#pragma unroll
      for (int m = 1; m < 16; m <<= 1) rs[r] += __shfl_xor(rs[r], m, 64);
      lrun[r] += rs[r];
    }
    // P (C-layout) -> LDS -> reload in A-layout (wave-local, no block barrier needed)
#pragma unroll
    for (int n = 0; n < 4; ++n)
#pragma unroll
      for (int r = 0; r < 4; ++r)
        Ps[w][((lane >> 4) * 4 + r) * 72 + n * 16 + la] = (_Float16)pv[n][r];
    asm volatile("s_waitcnt lgkmcnt(0)" ::: "memory");
    h8 pf[2];
#pragma unroll
    for (int ks = 0; ks < 2; ++ks)
      pf[ks] = *(const h8*)&Ps[w][la * 72 + ks * 32 + lb];
#pragma unroll
    for (int f = 0; f < 8; ++f)
#pragma unroll
      for (int ks = 0; ks < 2; ++ks) {
        h8 bv = *(const h8*)&Vt[(f * 16 + la) * 72 + ks * 32 + lb];
        oacc[f] = __builtin_amdgcn_mfma_f32_16x16x32_f16(pf[ks], bv, oacc[f], 0, 0, 0);
      }
    __syncthreads();
  }

  _Float16* Cg = ctx + ((size_t)(b * NS + qt * 64 + w * 16 + (lane >> 4) * 4)) * ND + h * NHD + la;
  float inv_l[4];
#pragma unroll
  for (int r = 0; r < 4; ++r) inv_l[r] = 1.0f / lrun[r];
#pragma unroll
  for (int f = 0; f < 8; ++f)
#pragma unroll
    for (int r = 0; r < 4; ++r)
      Cg[(size_t)r * ND + f * 16] = (_Float16)(oacc[f][r] * inv_l[r]);
}

// ---------------- launch ----------------

extern "C" void kernel_launch(void* const* d_in, const int* in_sizes, int n_in,
                              void* d_out, int out_size, void* d_ws, size_t ws_size,
                              hipStream_t stream) {
  (void)in_sizes; (void)n_in; (void)out_size; (void)ws_size;
  const float* x = (const float*)d_in[0];
  const float* wq = (const float*)d_in[1];
  const float* bq = (const float*)d_in[2];
  const float* wk = (const float*)d_in[3];
  const float* bk = (const float*)d_in[4];
  const float* wv = (const float*)d_in[5];
  const float* bv = (const float*)d_in[6];
  const float* wo = (const float*)d_in[7];
  const float* bo = (const float*)d_in[8];
  const float* qns = (const float*)d_in[9];
  const float* kns = (const float*)d_in[10];

  char* ws = (char*)d_ws;
  size_t off = 0;
  _Float16* xh = (_Float16*)(ws + off); off += (size_t)NM * ND * 2;
  _Float16* wqt = (_Float16*)(ws + off); off += (size_t)ND * ND * 2;
  _Float16* wkt = (_Float16*)(ws + off); off += (size_t)NKD * ND * 2;
  _Float16* wvt = (_Float16*)(ws + off); off += (size_t)NKD * ND * 2;
  _Float16* wot = (_Float16*)(ws + off); off += (size_t)ND * ND * 2;
  _Float16* Qb = (_Float16*)(ws + off); off += (size_t)NM * ND * 2;
  _Float16* Kbuf = (_Float16*)(ws + off); off += (size_t)NM * NKD * 2;
  _Float16* Vbuf = (_Float16*)(ws + off); off += (size_t)NM * NKD * 2;
  float* cosT = (float*)(ws + off); off += (size_t)NS * 64 * 4;
  float* sinT = (float*)(ws + off); off += (size_t)NS * 64 * 4;
  _Float16* ctx = xh;  // xh dead after V GEMM; reuse as attention output

  cvt_x_kernel<<<NM * ND / 8 / 256, 256, 0, stream>>>(x, xh, NM * ND / 8);
  wtrans_kernel<<<dim3(ND / 64, ND / 64), 256, 0, stream>>>(wq, wqt, ND, ND);
  wtrans_kernel<<<dim3(NKD / 64, ND / 64), 256, 0, stream>>>(wk, wkt, ND, NKD);
  wtrans_kernel<<<dim3(NKD / 64, ND / 64), 256, 0, stream>>>(wv, wvt, ND, NKD);
  wtrans_kernel<<<dim3(ND / 64, ND / 64), 256, 0, stream>>>(wo, wot, ND, ND);
  rope_tables_kernel<<<NS * 64 / 256, 256, 0, stream>>>(cosT, sinT);

  gemm_bt_kernel<_Float16><<<dim3(ND / 128, NM / 128), 256, 0, stream>>>(xh, wqt, bq, Qb, ND, ND);
  gemm_bt_kernel<_Float16><<<dim3(NKD / 128, NM / 128), 256, 0, stream>>>(xh, wkt, bk, Kbuf, NKD, ND);
  gemm_bt_kernel<_Float16><<<dim3(NKD / 128, NM / 128), 256, 0, stream>>>(xh, wvt, bv, Vbuf, NKD, ND);

  norm_rope_kernel<<<NM * NH / 4, 256, 0, stream>>>(Qb, qns, cosT, sinT, 4, ND, HEAD_SCALE);
  norm_rope_kernel<<<NM * NG / 4, 256, 0, stream>>>(Kbuf, kns, cosT, sinT, 2, NKD, 1.0f);

  attn_kernel<<<dim3(NS / 64, NH, NB), 256, 0, stream>>>(Qb, Kbuf, Vbuf, ctx);

  gemm_bt_kernel<float><<<dim3(ND / 128, NM / 128), 256, 0, stream>>>(ctx, wot, bo, (float*)d_out, ND, ND);
}

// Round 2
// 474.891 us; speedup vs baseline: 1.1832x; 1.1832x over previous
//
#include <hip/hip_runtime.h>

// Problem constants
#define NB 16
#define NS 512
#define ND 2048
#define NH 16
#define NG 4
#define NHD 128
#define NM (NB * NS)      // 8192 rows (b*s)
#define NKD (NG * NHD)    // 512
#define NKV 1024          // fused K|V row width
#define HEAD_SCALE 0.08838834764831845f

typedef _Float16 h8 __attribute__((ext_vector_type(8)));
typedef float fx4 __attribute__((ext_vector_type(4)));

// global -> LDS direct copy, 16B per lane. LDS dest is wave-uniform base + lane*16.
__device__ __forceinline__ void gload16(const void* g, void* l) {
  __builtin_amdgcn_global_load_lds(
      (__attribute__((address_space(1))) void*)(unsigned long long)g,
      (__attribute__((address_space(3))) void*)(unsigned long long)l,
      16, 0, 0);
}

// ---------------- prep kernels ----------------

__global__ void cvt_x_kernel(const float* __restrict__ in, _Float16* __restrict__ out, int n8) {
  int i = blockIdx.x * 256 + threadIdx.x;
  if (i >= n8) return;
  const fx4* p = (const fx4*)in;
  fx4 a = p[2 * i], b = p[2 * i + 1];
  h8 h;
  h[0] = (_Float16)a[0]; h[1] = (_Float16)a[1]; h[2] = (_Float16)a[2]; h[3] = (_Float16)a[3];
  h[4] = (_Float16)b[0]; h[5] = (_Float16)b[1]; h[6] = (_Float16)b[2]; h[7] = (_Float16)b[3];
  ((h8*)out)[i] = h;
}

// w[K][N] f32 -> wt[N][K] f16 (64x64 LDS tile transpose)
__global__ void wtrans_kernel(const float* __restrict__ w, _Float16* __restrict__ wt, int K, int N) {
  __shared__ float t[64][65];
  int n0 = blockIdx.x * 64, k0 = blockIdx.y * 64;
#pragma unroll
  for (int it = 0; it < 16; ++it) {
    int idx = it * 256 + threadIdx.x;
    int r = idx >> 6, c = idx & 63;
    t[r][c] = w[(size_t)(k0 + r) * N + n0 + c];
  }
  __syncthreads();
#pragma unroll
  for (int it = 0; it < 16; ++it) {
    int idx = it * 256 + threadIdx.x;
    int r = idx >> 6, c = idx & 63;
    wt[(size_t)(n0 + r) * K + k0 + c] = (_Float16)t[c][r];
  }
}

// V part of fused KV buffer -> Vt[b*4+g][128 d][512 s]
__global__ void vtrans_kernel(const _Float16* __restrict__ kv, _Float16* __restrict__ vt) {
  __shared__ _Float16 t[64][72];
  int st = blockIdx.x, dt = blockIdx.y, bg = blockIdx.z;
  int b = bg >> 2, g = bg & 3;
  const _Float16* src = kv + ((size_t)(b * NS + st * 64)) * NKV + NKD + g * NHD + dt * 64;
#pragma unroll
  for (int it = 0; it < 2; ++it) {
    int idx = it * 256 + threadIdx.x;  // 512 h8 chunks = 64x64 tile
    int r = idx >> 3, c = (idx & 7) * 8;
    *(h8*)&t[r][c] = *(const h8*)(src + (size_t)r * NKV + c);
  }
  __syncthreads();
  _Float16* dst = vt + ((size_t)bg * NHD + dt * 64) * NS + st * 64;
#pragma unroll
  for (int it = 0; it < 2; ++it) {
    int idx = it * 256 + threadIdx.x;
    int r = idx >> 3, c = (idx & 7) * 8;  // r = d within tile, c = kv cols
    h8 o;
#pragma unroll
    for (int e = 0; e < 8; ++e) o[e] = t[c + e][r];
    *(h8*)(dst + (size_t)r * NS + c) = o;
  }
}

__global__ void rope_tables_kernel(float* __restrict__ cosT, float* __restrict__ sinT) {
  int i = blockIdx.x * 256 + threadIdx.x;  // 512*64 total
  int s = i >> 6, f = i & 63;
  float inv = exp2f(-(float)f * (13.287712379549449f / 64.0f));
  float a = (float)s * inv;
  cosT[i] = cosf(a);
  sinT[i] = sinf(a);
}

// per (row, head): RMSNorm over 128, RoPE, *outScale, in-place f16
__global__ void norm_rope_kernel(_Float16* __restrict__ X, const float* __restrict__ scale,
                                 const float* __restrict__ cosT, const float* __restrict__ sinT,
                                 int hshift, int rowStride, float outScale) {
  int wid = threadIdx.x >> 6, lane = threadIdx.x & 63;
  int task = blockIdx.x * 4 + wid;
  int row = task >> hshift;
  int head = task & ((1 << hshift) - 1);
  _Float16* p = X + (size_t)row * rowStride + head * NHD;
  float x1 = (float)p[lane], x2 = (float)p[lane + 64];
  float ss = x1 * x1 + x2 * x2;
#pragma unroll
  for (int m = 1; m < 64; m <<= 1) ss += __shfl_xor(ss, m, 64);
  float rn = rsqrtf(ss * (1.0f / 128.0f) + 1e-6f);
  int s = row & (NS - 1);
  float c = cosT[s * 64 + lane], sn = sinT[s * 64 + lane];
  float n1 = x1 * rn * scale[lane], n2 = x2 * rn * scale[64 + lane];
  p[lane] = (_Float16)((n1 * c - n2 * sn) * outScale);
  p[lane + 64] = (_Float16)((n1 * sn + n2 * c) * outScale);
}

// ---------------- GEMM: C[M][N] = A[M][K](f16) * Bt[N][K]^T + bias ----------------

__device__ __forceinline__ void st_out(float* p, float v) { *p = v; }
__device__ __forceinline__ void st_out(_Float16* p, float v) { *p = (_Float16)v; }

template <typename OT>
__global__ __launch_bounds__(256, 3) void gemm_bt_kernel(
    const _Float16* __restrict__ A, const _Float16* __restrict__ Bt,
    const float* __restrict__ bias, OT* __restrict__ C, int N, int K) {
  __shared__ alignas(16) _Float16 As[128 * 64];
  __shared__ alignas(16) _Float16 Bs[128 * 64];
  const int tid = threadIdx.x;
  const int lane = tid & 63, wid = tid >> 6;
  const int wr = wid >> 1, wc = wid & 1;
  const int la = lane & 15, lb = (lane >> 4) * 8;
  const int bm = blockIdx.y * 128, bn = blockIdx.x * 128;

  fx4 acc[4][4] = {};

  for (int kt = 0; kt < K; kt += 64) {
    const _Float16* Ag = A + (size_t)bm * K + kt;
    const _Float16* Bg = Bt + (size_t)bn * K + kt;
#pragma unroll
    for (int it = 0; it < 4; ++it) {
      int cb = it * 256 + wid * 64;  // wave-uniform chunk base
      int ca = cb + lane;
      int r = ca >> 3, cc = ca & 7;
      gload16(Ag + (size_t)r * K + cc * 8, &As[cb * 8]);
      gload16(Bg + (size_t)r * K + cc * 8, &Bs[cb * 8]);
    }
    __syncthreads();
#pragma unroll
    for (int kk = 0; kk < 2; ++kk) {
      h8 af[4], bf[4];
#pragma unroll
      for (int m = 0; m < 4; ++m)
        af[m] = *(const h8*)&As[(wr * 64 + m * 16 + la) * 64 + kk * 32 + lb];
#pragma unroll
      for (int n = 0; n < 4; ++n)
        bf[n] = *(const h8*)&Bs[(wc * 64 + n * 16 + la) * 64 + kk * 32 + lb];
#pragma unroll
      for (int m = 0; m < 4; ++m)
#pragma unroll
        for (int n = 0; n < 4; ++n)
          acc[m][n] = __builtin_amdgcn_mfma_f32_16x16x32_f16(af[m], bf[n], acc[m][n], 0, 0, 0);
    }
    __syncthreads();
  }
#pragma unroll
  for (int m = 0; m < 4; ++m) {
    int row0 = bm + wr * 64 + m * 16 + (lane >> 4) * 4;
#pragma unroll
    for (int n = 0; n < 4; ++n) {
      int col = bn + wc * 64 + n * 16 + la;
      float bvv = bias[col];
#pragma unroll
      for (int r = 0; r < 4; ++r)
        st_out(&C[(size_t)(row0 + r) * N + col], acc[m][n][r] + bvv);
    }
  }
}

// ---------------- flash attention ----------------
// grid (S/64, NH, NB); 4 waves, each owns 16 q-rows. Q pre-scaled by HEAD_SCALE;
// logits get another *HEAD_SCALE (reference applies it twice).
// All LDS tiles XOR-chunk-swizzled (c ^= row&7 on 16B chunks) via pre-swizzled
// global source for gload_lds + same XOR on reads (rule-21 involution).

__global__ __launch_bounds__(256, 4) void attn_kernel(
    const _Float16* __restrict__ Q, const _Float16* __restrict__ KV,
    const _Float16* __restrict__ Vt, _Float16* __restrict__ ctx) {
  const int qt = blockIdx.x, h = blockIdx.y, b = blockIdx.z;
  const int g = h >> 2;
  const int lane = threadIdx.x & 63, w = threadIdx.x >> 6;
  const int la = lane & 15, lq = lane >> 4, lb = lq * 8;
  __shared__ alignas(16) _Float16 Ks[64 * 128];   // [kv][d], swizzled
  __shared__ alignas(16) _Float16 Vs[128 * 64];   // [d][kv], swizzled
  __shared__ alignas(16) _Float16 Ps[4][16 * 64]; // per-wave P, swizzled

  h8 qf[4];
  {
    const _Float16* Qg = Q + ((size_t)(b * NS + qt * 64 + w * 16 + la)) * ND + h * NHD + lb;
#pragma unroll
    for (int kc = 0; kc < 4; ++kc) qf[kc] = *(const h8*)(Qg + kc * 32);
  }

  float mrun[4], lrun[4];
  fx4 oacc[8] = {};
#pragma unroll
  for (int r = 0; r < 4; ++r) { mrun[r] = -1e30f; lrun[r] = 0.f; }

  const int qrow0 = qt * 64 + w * 16 + lq * 4;
  const _Float16* Vg = Vt + (size_t)(b * NG + g) * NHD * NS;

  for (int kt = 0; kt <= qt; ++kt) {
    const _Float16* Kg = KV + ((size_t)(b * NS + kt * 64)) * NKV + g * NHD;
#pragma unroll
    for (int it = 0; it < 4; ++it) {  // K tile: 64 rows x 16 chunks
      int cb = it * 256 + w * 64;
      int s = cb + lane;
      int rr = s >> 4, c = s & 15;
      gload16(Kg + (size_t)rr * NKV + (size_t)((c ^ (rr & 7)) * 8), &Ks[cb * 8]);
    }
#pragma unroll
    for (int it = 0; it < 4; ++it) {  // Vt tile: 128 rows x 8 chunks
      int cb = it * 256 + w * 64;
      int s = cb + lane;
      int rr = s >> 3, c = s & 7;
      gload16(Vg + (size_t)rr * NS + kt * 64 + (size_t)((c ^ (rr & 7)) * 8), &Vs[cb * 8]);
    }
    __syncthreads();

    // QK^T: 16 q-rows x 64 kv
    fx4 sc[4] = {};
    __builtin_amdgcn_s_setprio(1);
#pragma unroll
    for (int n = 0; n < 4; ++n) {
      int row = n * 16 + la;
#pragma unroll
      for (int kc = 0; kc < 4; ++kc) {
        h8 bk = *(const h8*)&Ks[row * 128 + ((kc * 4 + lq) ^ (la & 7)) * 8];
        sc[n] = __builtin_amdgcn_mfma_f32_16x16x32_f16(qf[kc], bk, sc[n], 0, 0, 0);
      }
    }
    __builtin_amdgcn_s_setprio(0);

    float pv[4][4];
    float rm[4] = {-1e30f, -1e30f, -1e30f, -1e30f};
#pragma unroll
    for (int n = 0; n < 4; ++n) {
      int kv = kt * 64 + n * 16 + la;
#pragma unroll
      for (int r = 0; r < 4; ++r) {
        float sv = sc[n][r] * HEAD_SCALE;
        sv = (kv > qrow0 + r) ? -1e30f : sv;
        pv[n][r] = sv;
        rm[r] = fmaxf(rm[r], sv);
      }
    }
#pragma unroll
    for (int r = 0; r < 4; ++r) {
#pragma unroll
      for (int m = 1; m < 16; m <<= 1) rm[r] = fmaxf(rm[r], __shfl_xor(rm[r], m, 64));
      float mn = fmaxf(mrun[r], rm[r]);
      float corr = __expf(mrun[r] - mn);
      mrun[r] = mn;
      lrun[r] *= corr;
#pragma unroll
      for (int f = 0; f < 8; ++f) oacc[f][r] *= corr;
    }
    float rs[4] = {0.f, 0.f, 0.f, 0.f};
#pragma unroll
    for (int n = 0; n < 4; ++n)
#pragma unroll
      for (int r = 0; r < 4; ++r) {
        float e = __expf(pv[n][r] - mrun[r]);
        pv[n][r] = e;
        rs[r] += e;
      }
#pragma unroll
    for (int r = 0; r < 4; ++r) {
#pragma unroll
      for (int m = 1; m < 16; m <<= 1) rs[r] += __shfl_xor(rs[r], m, 64);
      lrun[r] += rs[r];
    }
    // P (C-layout) -> LDS (swizzled) -> reload in A-layout (wave-local)
#pragma unroll
    for (int n = 0; n < 4; ++n)
#pragma unroll
      for (int r = 0; r < 4; ++r) {
        int row = lq * 4 + r;
        int chsw = (n * 2 + (la >> 3)) ^ (row & 7);
        Ps[w][row * 64 + chsw * 8 + (la & 7)] = (_Float16)pv[n][r];
      }
    asm volatile("s_waitcnt lgkmcnt(0)" ::: "memory");
    h8 pf[2];
#pragma unroll
    for (int ks = 0; ks < 2; ++ks)
      pf[ks] = *(const h8*)&Ps[w][la * 64 + ((ks * 4 + lq) ^ (la & 7)) * 8];
    __builtin_amdgcn_s_setprio(1);
#pragma unroll
    for (int f = 0; f < 8; ++f) {
      int row = f * 16 + la;
#pragma unroll
      for (int ks = 0; ks < 2; ++ks) {
        h8 bv = *(const h8*)&Vs[row * 64 + ((ks * 4 + lq) ^ (la & 7)) * 8];
        oacc[f] = __builtin_amdgcn_mfma_f32_16x16x32_f16(pf[ks], bv, oacc[f], 0, 0, 0);
      }
    }
    __builtin_amdgcn_s_setprio(0);
    __syncthreads();
  }

  _Float16* Cg = ctx + ((size_t)(b * NS + qt * 64 + w * 16 + lq * 4)) * ND + h * NHD + la;
  float inv_l[4];
#pragma unroll
  for (int r = 0; r < 4; ++r) inv_l[r] = 1.0f / lrun[r];
#pragma unroll
  for (int f = 0; f < 8; ++f)
#pragma unroll
    for (int r = 0; r < 4; ++r)
      Cg[(size_t)r * ND + f * 16] = (_Float16)(oacc[f][r] * inv_l[r]);
}

// ---------------- launch ----------------

extern "C" void kernel_launch(void* const* d_in, const int* in_sizes, int n_in,
                              void* d_out, int out_size, void* d_ws, size_t ws_size,
                              hipStream_t stream) {
  (void)in_sizes; (void)n_in; (void)out_size; (void)ws_size;
  const float* x = (const float*)d_in[0];
  const float* wq = (const float*)d_in[1];
  const float* bq = (const float*)d_in[2];
  const float* wk = (const float*)d_in[3];
  const float* bk = (const float*)d_in[4];
  const float* wv = (const float*)d_in[5];
  const float* bv = (const float*)d_in[6];
  const float* wo = (const float*)d_in[7];
  const float* bo = (const float*)d_in[8];
  const float* qns = (const float*)d_in[9];
  const float* kns = (const float*)d_in[10];

  char* ws = (char*)d_ws;
  size_t off = 0;
  _Float16* xh = (_Float16*)(ws + off); off += (size_t)NM * ND * 2;       // 32MB
  _Float16* wqt = (_Float16*)(ws + off); off += (size_t)ND * ND * 2;      // 8MB
  _Float16* wkvt = (_Float16*)(ws + off); off += (size_t)NKV * ND * 2;    // 4MB
  _Float16* wot = (_Float16*)(ws + off); off += (size_t)ND * ND * 2;      // 8MB
  _Float16* Qb = (_Float16*)(ws + off); off += (size_t)NM * ND * 2;       // 32MB
  _Float16* KVbuf = (_Float16*)(ws + off); off += (size_t)NM * NKV * 2;   // 16MB
  float* cosT = (float*)(ws + off); off += (size_t)NS * 64 * 4;
  float* sinT = (float*)(ws + off); off += (size_t)NS * 64 * 4;
  float* bkv = (float*)(ws + off); off += (size_t)NKV * 4;
  _Float16* ctx = xh;            // xh dead after KV GEMM; reuse
  _Float16* Vtg = wqt;           // wqt dead after Q GEMM; reuse (needs 8MB)

  cvt_x_kernel<<<NM * ND / 8 / 256, 256, 0, stream>>>(x, xh, NM * ND / 8);
  wtrans_kernel<<<dim3(ND / 64, ND / 64), 256, 0, stream>>>(wq, wqt, ND, ND);
  wtrans_kernel<<<dim3(NKD / 64, ND / 64), 256, 0, stream>>>(wk, wkvt, ND, NKD);
  wtrans_kernel<<<dim3(NKD / 64, ND / 64), 256, 0, stream>>>(wv, wkvt + (size_t)NKD * ND, ND, NKD);
  wtrans_kernel<<<dim3(ND / 64, ND / 64), 256, 0, stream>>>(wo, wot, ND, ND);
  rope_tables_kernel<<<NS * 64 / 256, 256, 0, stream>>>(cosT, sinT);
  hipMemcpyAsync(bkv, bk, NKD * sizeof(float), hipMemcpyDeviceToDevice, stream);
  hipMemcpyAsync(bkv + NKD, bv, NKD * sizeof(float), hipMemcpyDeviceToDevice, stream);

  gemm_bt_kernel<_Float16><<<dim3(ND / 128, NM / 128), 256, 0, stream>>>(xh, wqt, bq, Qb, ND, ND);
  gemm_bt_kernel<_Float16><<<dim3(NKV / 128, NM / 128), 256, 0, stream>>>(xh, wkvt, bkv, KVbuf, NKV, ND);

  norm_rope_kernel<<<NM * NH / 4, 256, 0, stream>>>(Qb, qns, cosT, sinT, 4, ND, HEAD_SCALE);
  norm_rope_kernel<<<NM * NG / 4, 256, 0, stream>>>(KVbuf, kns, cosT, sinT, 2, NKV, 1.0f);

  vtrans_kernel<<<dim3(NS / 64, NHD / 64, NB * NG), 256, 0, stream>>>(KVbuf, Vtg);

  attn_kernel<<<dim3(NS / 64, NH, NB), 256, 0, stream>>>(Qb, KVbuf, Vtg, ctx);

  gemm_bt_kernel<float><<<dim3(ND / 128, NM / 128), 256, 0, stream>>>(ctx, wot, bo, (float*)d_out, ND, ND);
}

// Round 3
// 368.422 us; speedup vs baseline: 1.5252x; 1.2890x over previous
//
#include <hip/hip_runtime.h>

// Problem constants
#define NB 16
#define NS 512
#define ND 2048
#define NH 16
#define NG 4
#define NHD 128
#define NM (NB * NS)      // 8192 rows (b*s)
#define NKD (NG * NHD)    // 512
#define NKV 1024          // fused K|V row width
#define HEAD_SCALE 0.08838834764831845f

typedef _Float16 h8 __attribute__((ext_vector_type(8)));
typedef float fx4 __attribute__((ext_vector_type(4)));

// global -> LDS direct copy, 16B per lane. LDS dest is wave-uniform base + lane*16.
__device__ __forceinline__ void gload16(const void* g, void* l) {
  __builtin_amdgcn_global_load_lds(
      (__attribute__((address_space(1))) void*)(unsigned long long)g,
      (__attribute__((address_space(3))) void*)(unsigned long long)l,
      16, 0, 0);
}

// ---------------- prep kernels ----------------

__global__ void cvt_x_kernel(const float* __restrict__ in, _Float16* __restrict__ out, int n8) {
  int i = blockIdx.x * 256 + threadIdx.x;
  if (i >= n8) return;
  const fx4* p = (const fx4*)in;
  fx4 a = p[2 * i], b = p[2 * i + 1];
  h8 h;
  h[0] = (_Float16)a[0]; h[1] = (_Float16)a[1]; h[2] = (_Float16)a[2]; h[3] = (_Float16)a[3];
  h[4] = (_Float16)b[0]; h[5] = (_Float16)b[1]; h[6] = (_Float16)b[2]; h[7] = (_Float16)b[3];
  ((h8*)out)[i] = h;
}

// w[K][N] f32 -> wt[N][K] f16 (64x64 LDS tile transpose)
__global__ void wtrans_kernel(const float* __restrict__ w, _Float16* __restrict__ wt, int K, int N) {
  __shared__ float t[64][65];
  int n0 = blockIdx.x * 64, k0 = blockIdx.y * 64;
#pragma unroll
  for (int it = 0; it < 16; ++it) {
    int idx = it * 256 + threadIdx.x;
    int r = idx >> 6, c = idx & 63;
    t[r][c] = w[(size_t)(k0 + r) * N + n0 + c];
  }
  __syncthreads();
#pragma unroll
  for (int it = 0; it < 16; ++it) {
    int idx = it * 256 + threadIdx.x;
    int r = idx >> 6, c = idx & 63;
    wt[(size_t)(n0 + r) * K + k0 + c] = (_Float16)t[c][r];
  }
}

// V part of fused KV buffer -> Vt[b*4+g][128 d][512 s]
__global__ void vtrans_kernel(const _Float16* __restrict__ kv, _Float16* __restrict__ vt) {
  __shared__ _Float16 t[64][72];
  int st = blockIdx.x, dt = blockIdx.y, bg = blockIdx.z;
  int b = bg >> 2, g = bg & 3;
  const _Float16* src = kv + ((size_t)(b * NS + st * 64)) * NKV + NKD + g * NHD + dt * 64;
#pragma unroll
  for (int it = 0; it < 2; ++it) {
    int idx = it * 256 + threadIdx.x;  // 512 h8 chunks = 64x64 tile
    int r = idx >> 3, c = (idx & 7) * 8;
    *(h8*)&t[r][c] = *(const h8*)(src + (size_t)r * NKV + c);
  }
  __syncthreads();
  _Float16* dst = vt + ((size_t)bg * NHD + dt * 64) * NS + st * 64;
#pragma unroll
  for (int it = 0; it < 2; ++it) {
    int idx = it * 256 + threadIdx.x;
    int r = idx >> 3, c = (idx & 7) * 8;  // r = d within tile, c = kv cols
    h8 o;
#pragma unroll
    for (int e = 0; e < 8; ++e) o[e] = t[c + e][r];
    *(h8*)(dst + (size_t)r * NS + c) = o;
  }
}

__global__ void rope_tables_kernel(float* __restrict__ cosT, float* __restrict__ sinT) {
  int i = blockIdx.x * 256 + threadIdx.x;  // 512*64 total
  int s = i >> 6, f = i & 63;
  float inv = exp2f(-(float)f * (13.287712379549449f / 64.0f));
  float a = (float)s * inv;
  cosT[i] = cosf(a);
  sinT[i] = sinf(a);
}

// per (row, head): RMSNorm over 128, RoPE, *outScale, in-place f16
__global__ void norm_rope_kernel(_Float16* __restrict__ X, const float* __restrict__ scale,
                                 const float* __restrict__ cosT, const float* __restrict__ sinT,
                                 int hshift, int rowStride, float outScale) {
  int wid = threadIdx.x >> 6, lane = threadIdx.x & 63;
  int task = blockIdx.x * 4 + wid;
  int row = task >> hshift;
  int head = task & ((1 << hshift) - 1);
  _Float16* p = X + (size_t)row * rowStride + head * NHD;
  float x1 = (float)p[lane], x2 = (float)p[lane + 64];
  float ss = x1 * x1 + x2 * x2;
#pragma unroll
  for (int m = 1; m < 64; m <<= 1) ss += __shfl_xor(ss, m, 64);
  float rn = rsqrtf(ss * (1.0f / 128.0f) + 1e-6f);
  int s = row & (NS - 1);
  float c = cosT[s * 64 + lane], sn = sinT[s * 64 + lane];
  float n1 = x1 * rn * scale[lane], n2 = x2 * rn * scale[64 + lane];
  p[lane] = (_Float16)((n1 * c - n2 * sn) * outScale);
  p[lane + 64] = (_Float16)((n1 * sn + n2 * c) * outScale);
}

// ---------------- GEMM: C[M][N] = A[M][K](f16) * Bt[N][K]^T + bias ----------------

__device__ __forceinline__ void st_out(float* p, float v) { *p = v; }
__device__ __forceinline__ void st_out(_Float16* p, float v) { *p = (_Float16)v; }

template <typename OT>
__global__ __launch_bounds__(256, 3) void gemm_bt_kernel(
    const _Float16* __restrict__ A, const _Float16* __restrict__ Bt,
    const float* __restrict__ bias, OT* __restrict__ C, int N, int K) {
  __shared__ alignas(16) _Float16 As[128 * 64];
  __shared__ alignas(16) _Float16 Bs[128 * 64];
  const int tid = threadIdx.x;
  const int lane = tid & 63, wid = tid >> 6;
  const int wr = wid >> 1, wc = wid & 1;
  const int la = lane & 15, lb = (lane >> 4) * 8;
  const int bm = blockIdx.y * 128, bn = blockIdx.x * 128;

  fx4 acc[4][4] = {};

  for (int kt = 0; kt < K; kt += 64) {
    const _Float16* Ag = A + (size_t)bm * K + kt;
    const _Float16* Bg = Bt + (size_t)bn * K + kt;
#pragma unroll
    for (int it = 0; it < 4; ++it) {
      int cb = it * 256 + wid * 64;  // wave-uniform chunk base
      int ca = cb + lane;
      int r = ca >> 3, cc = ca & 7;
      gload16(Ag + (size_t)r * K + cc * 8, &As[cb * 8]);
      gload16(Bg + (size_t)r * K + cc * 8, &Bs[cb * 8]);
    }
    __syncthreads();
#pragma unroll
    for (int kk = 0; kk < 2; ++kk) {
      h8 af[4], bf[4];
#pragma unroll
      for (int m = 0; m < 4; ++m)
        af[m] = *(const h8*)&As[(wr * 64 + m * 16 + la) * 64 + kk * 32 + lb];
#pragma unroll
      for (int n = 0; n < 4; ++n)
        bf[n] = *(const h8*)&Bs[(wc * 64 + n * 16 + la) * 64 + kk * 32 + lb];
#pragma unroll
      for (int m = 0; m < 4; ++m)
#pragma unroll
        for (int n = 0; n < 4; ++n)
          acc[m][n] = __builtin_amdgcn_mfma_f32_16x16x32_f16(af[m], bf[n], acc[m][n], 0, 0, 0);
    }
    __syncthreads();
  }
#pragma unroll
  for (int m = 0; m < 4; ++m) {
    int row0 = bm + wr * 64 + m * 16 + (lane >> 4) * 4;
#pragma unroll
    for (int n = 0; n < 4; ++n) {
      int col = bn + wc * 64 + n * 16 + la;
      float bvv = bias[col];
#pragma unroll
      for (int r = 0; r < 4; ++r)
        st_out(&C[(size_t)(row0 + r) * N + col], acc[m][n][r] + bvv);
    }
  }
}

// ---------------- flash attention ----------------
// 512 blocks x 512 threads. Block = (q-tile pair {j,15-j}, group g, batch b):
// processes all 4 heads of the group; wave = (head, 16 q-rows). Each block does
// exactly 9 kt-tiles total (causal-balanced). K/V LDS double-buffered, one
// barrier per tile: stage(next) issued right after barrier, compute overlaps.
// XCD-chunk swizzle: each XCD covers 2 batches -> 2MB KV set fits its L2.

__global__ __launch_bounds__(512, 4) void attn_kernel(
    const _Float16* __restrict__ Q, const _Float16* __restrict__ KV,
    const _Float16* __restrict__ Vt, _Float16* __restrict__ ctx) {
  __shared__ alignas(16) _Float16 Ks[2][64 * 128];   // [kv][d], swizzled
  __shared__ alignas(16) _Float16 Vs[2][128 * 64];   // [d][kv], swizzled
  __shared__ alignas(16) _Float16 Ps[8][16 * 64];    // per-wave P, swizzled

  const int bid = blockIdx.x;
  const int logical = (bid & 7) * 64 + (bid >> 3);   // XCD chunk swizzle (512 = 8*64)
  const int b = logical >> 5;
  const int g = (logical >> 3) & 3;
  const int jp = logical & 7;
  const int j1 = jp, j2 = 15 - jp;

  const int tid = threadIdx.x;
  const int lane = tid & 63, w = tid >> 6;
  const int la = lane & 15, lq = lane >> 4;
  const int h = g * 4 + (w & 3);
  const int rh = w >> 2;

  const _Float16* Vg = Vt + (size_t)(b * NG + g) * NHD * NS;

  auto stage = [&](int buf, int kt) {
    const _Float16* Kg = KV + ((size_t)(b * NS + kt * 64)) * NKV + g * NHD;
#pragma unroll
    for (int it = 0; it < 2; ++it) {
      int cb = it * 512 + w * 64;
      int s = cb + lane;
      int rr = s >> 4, c = s & 15;
      gload16(Kg + (size_t)rr * NKV + ((c ^ (rr & 7)) * 8), &Ks[buf][cb * 8]);
    }
#pragma unroll
    for (int it = 0; it < 2; ++it) {
      int cb = it * 512 + w * 64;
      int s = cb + lane;
      int rr = s >> 3, c = s & 7;
      gload16(Vg + (size_t)rr * NS + kt * 64 + ((c ^ (rr & 7)) * 8), &Vs[buf][cb * 8]);
    }
  };

  const int nt1 = ((j1 * 32 + 31) >> 6) + 1;
  const int nt2 = ((j2 * 32 + 31) >> 6) + 1;
  const int ntotal = nt1 + nt2;  // == 9

  h8 qf[4];
  fx4 oacc[8];
  float mrun[4], lrun[4];

  stage(0, 0);
  int cur = 0;
  for (int t = 0; t < ntotal; ++t) {
    const bool inA = t < nt1;
    const int j = inA ? j1 : j2;
    const int kt = inA ? t : t - nt1;
    const int ntj = inA ? nt1 : nt2;
    __syncthreads();  // drains vmcnt(0): buf[cur] staged; all waves done with buf[cur^1]
    if (t + 1 < ntotal) {
      int nkt = (t + 1 < nt1) ? (t + 1) : (t + 1 - nt1);
      stage(cur ^ 1, nkt);
    }
    if (kt == 0) {  // new q-tile: load Q frags, reset online-softmax state
      const _Float16* Qg = Q + ((size_t)(b * NS + j * 32 + rh * 16 + la)) * ND + h * NHD + lq * 8;
#pragma unroll
      for (int kc = 0; kc < 4; ++kc) qf[kc] = *(const h8*)(Qg + kc * 32);
#pragma unroll
      for (int f = 0; f < 8; ++f) oacc[f] = fx4{0.f, 0.f, 0.f, 0.f};
#pragma unroll
      for (int r = 0; r < 4; ++r) { mrun[r] = -1e30f; lrun[r] = 0.f; }
    }

    // QK^T: 16 q-rows x 64 kv
    fx4 sc[4] = {};
    __builtin_amdgcn_s_setprio(1);
#pragma unroll
    for (int n = 0; n < 4; ++n) {
      int row = n * 16 + la;
#pragma unroll
      for (int kc = 0; kc < 4; ++kc) {
        h8 bk = *(const h8*)&Ks[cur][row * 128 + (((kc * 4 + lq) ^ (la & 7)) * 8)];
        sc[n] = __builtin_amdgcn_mfma_f32_16x16x32_f16(qf[kc], bk, sc[n], 0, 0, 0);
      }
    }
    __builtin_amdgcn_s_setprio(0);

    const int qrow0 = j * 32 + rh * 16 + lq * 4;
    const bool maskT = (kt == ntj - 1);  // only the diagonal tile needs masking
    float pv[4][4];
    float rm[4] = {-1e30f, -1e30f, -1e30f, -1e30f};
#pragma unroll
    for (int n = 0; n < 4; ++n) {
      int kv = kt * 64 + n * 16 + la;
#pragma unroll
      for (int r = 0; r < 4; ++r) {
        float sv = sc[n][r] * HEAD_SCALE;
        sv = (maskT && kv > qrow0 + r) ? -1e30f : sv;
        pv[n][r] = sv;
        rm[r] = fmaxf(rm[r], sv);
      }
    }
#pragma unroll
    for (int r = 0; r < 4; ++r) {
#pragma unroll
      for (int m = 1; m < 16; m <<= 1) rm[r] = fmaxf(rm[r], __shfl_xor(rm[r], m, 64));
      float mn = fmaxf(mrun[r], rm[r]);
      float corr = __expf(mrun[r] - mn);
      mrun[r] = mn;
      lrun[r] *= corr;
#pragma unroll
      for (int f = 0; f < 8; ++f) oacc[f][r] *= corr;
    }
    float rs[4] = {0.f, 0.f, 0.f, 0.f};
#pragma unroll
    for (int n = 0; n < 4; ++n)
#pragma unroll
      for (int r = 0; r < 4; ++r) {
        float e = __expf(pv[n][r] - mrun[r]);
        pv[n][r] = e;
        rs[r] += e;
      }
#pragma unroll
    for (int r = 0; r < 4; ++r) {
#pragma unroll
      for (int m = 1; m < 16; m <<= 1) rs[r] += __shfl_xor(rs[r], m, 64);
      lrun[r] += rs[r];
    }

    // P (C-layout) -> LDS (swizzled) -> reload in A-layout (wave-local)
#pragma unroll
    for (int n = 0; n < 4; ++n)
#pragma unroll
      for (int r = 0; r < 4; ++r) {
        int row = lq * 4 + r;
        int chsw = (n * 2 + (la >> 3)) ^ (row & 7);
        Ps[w][row * 64 + chsw * 8 + (la & 7)] = (_Float16)pv[n][r];
      }
    asm volatile("s_waitcnt lgkmcnt(0)" ::: "memory");
    __builtin_amdgcn_sched_barrier(0);
    h8 pf[2];
#pragma unroll
    for (int ks = 0; ks < 2; ++ks)
      pf[ks] = *(const h8*)&Ps[w][la * 64 + (((ks * 4 + lq) ^ (la & 7)) * 8)];

    // PV: oacc[16 rows][128 d]
    __builtin_amdgcn_s_setprio(1);
#pragma unroll
    for (int f = 0; f < 8; ++f) {
      int row = f * 16 + la;
#pragma unroll
      for (int ks = 0; ks < 2; ++ks) {
        h8 bv = *(const h8*)&Vs[cur][row * 64 + (((ks * 4 + lq) ^ (la & 7)) * 8)];
        oacc[f] = __builtin_amdgcn_mfma_f32_16x16x32_f16(pf[ks], bv, oacc[f], 0, 0, 0);
      }
    }
    __builtin_amdgcn_s_setprio(0);

    if (maskT) {  // last tile of this q-tile: write output
      _Float16* Cg = ctx + ((size_t)(b * NS + qrow0)) * ND + h * NHD + la;
      float inv_l[4];
#pragma unroll
      for (int r = 0; r < 4; ++r) inv_l[r] = 1.0f / lrun[r];
#pragma unroll
      for (int f = 0; f < 8; ++f)
#pragma unroll
        for (int r = 0; r < 4; ++r)
          Cg[(size_t)r * ND + f * 16] = (_Float16)(oacc[f][r] * inv_l[r]);
    }
    cur ^= 1;
  }
}

// ---------------- launch ----------------

extern "C" void kernel_launch(void* const* d_in, const int* in_sizes, int n_in,
                              void* d_out, int out_size, void* d_ws, size_t ws_size,
                              hipStream_t stream) {
  (void)in_sizes; (void)n_in; (void)out_size; (void)ws_size;
  const float* x = (const float*)d_in[0];
  const float* wq = (const float*)d_in[1];
  const float* bq = (const float*)d_in[2];
  const float* wk = (const float*)d_in[3];
  const float* bk = (const float*)d_in[4];
  const float* wv = (const float*)d_in[5];
  const float* bv = (const float*)d_in[6];
  const float* wo = (const float*)d_in[7];
  const float* bo = (const float*)d_in[8];
  const float* qns = (const float*)d_in[9];
  const float* kns = (const float*)d_in[10];

  char* ws = (char*)d_ws;
  size_t off = 0;
  _Float16* xh = (_Float16*)(ws + off); off += (size_t)NM * ND * 2;       // 32MB
  _Float16* wqt = (_Float16*)(ws + off); off += (size_t)ND * ND * 2;      // 8MB
  _Float16* wkvt = (_Float16*)(ws + off); off += (size_t)NKV * ND * 2;    // 4MB
  _Float16* wot = (_Float16*)(ws + off); off += (size_t)ND * ND * 2;      // 8MB
  _Float16* Qb = (_Float16*)(ws + off); off += (size_t)NM * ND * 2;       // 32MB
  _Float16* KVbuf = (_Float16*)(ws + off); off += (size_t)NM * NKV * 2;   // 16MB
  float* cosT = (float*)(ws + off); off += (size_t)NS * 64 * 4;
  float* sinT = (float*)(ws + off); off += (size_t)NS * 64 * 4;
  float* bkv = (float*)(ws + off); off += (size_t)NKV * 4;
  _Float16* ctx = xh;            // xh dead after KV GEMM; reuse
  _Float16* Vtg = wqt;           // wqt dead after Q GEMM; reuse (needs 8MB)

  cvt_x_kernel<<<NM * ND / 8 / 256, 256, 0, stream>>>(x, xh, NM * ND / 8);
  wtrans_kernel<<<dim3(ND / 64, ND / 64), 256, 0, stream>>>(wq, wqt, ND, ND);
  wtrans_kernel<<<dim3(NKD / 64, ND / 64), 256, 0, stream>>>(wk, wkvt, ND, NKD);
  wtrans_kernel<<<dim3(NKD / 64, ND / 64), 256, 0, stream>>>(wv, wkvt + (size_t)NKD * ND, ND, NKD);
  wtrans_kernel<<<dim3(ND / 64, ND / 64), 256, 0, stream>>>(wo, wot, ND, ND);
  rope_tables_kernel<<<NS * 64 / 256, 256, 0, stream>>>(cosT, sinT);
  hipMemcpyAsync(bkv, bk, NKD * sizeof(float), hipMemcpyDeviceToDevice, stream);
  hipMemcpyAsync(bkv + NKD, bv, NKD * sizeof(float), hipMemcpyDeviceToDevice, stream);

  gemm_bt_kernel<_Float16><<<dim3(ND / 128, NM / 128), 256, 0, stream>>>(xh, wqt, bq, Qb, ND, ND);
  gemm_bt_kernel<_Float16><<<dim3(NKV / 128, NM / 128), 256, 0, stream>>>(xh, wkvt, bkv, KVbuf, NKV, ND);

  norm_rope_kernel<<<NM * NH / 4, 256, 0, stream>>>(Qb, qns, cosT, sinT, 4, ND, HEAD_SCALE);
  norm_rope_kernel<<<NM * NG / 4, 256, 0, stream>>>(KVbuf, kns, cosT, sinT, 2, NKV, 1.0f);

  vtrans_kernel<<<dim3(NS / 64, NHD / 64, NB * NG), 256, 0, stream>>>(KVbuf, Vtg);

  attn_kernel<<<dim3(512), dim3(512), 0, stream>>>(Qb, KVbuf, Vtg, ctx);

  gemm_bt_kernel<float><<<dim3(ND / 128, NM / 128), 256, 0, stream>>>(ctx, wot, bo, (float*)d_out, ND, ND);
}

// Round 4
// 321.868 us; speedup vs baseline: 1.7457x; 1.1446x over previous
//
#include <hip/hip_runtime.h>

// Problem constants
#define NB 16
#define NS 512
#define ND 2048
#define NH 16
#define NG 4
#define NHD 128
#define NM (NB * NS)      // 8192 rows (b*s)
#define NKD (NG * NHD)    // 512
#define NKV 1024          // fused K|V row width
#define HEAD_SCALE 0.08838834764831845f

typedef _Float16 h8 __attribute__((ext_vector_type(8)));
typedef float fx4 __attribute__((ext_vector_type(4)));

// global -> LDS direct copy, 16B per lane. LDS dest is wave-uniform base + lane*16.
__device__ __forceinline__ void gload16(const void* g, void* l) {
  __builtin_amdgcn_global_load_lds(
      (__attribute__((address_space(1))) void*)(unsigned long long)g,
      (__attribute__((address_space(3))) void*)(unsigned long long)l,
      16, 0, 0);
}

// ---------------- prep kernels ----------------

__global__ void cvt_x_kernel(const float* __restrict__ in, _Float16* __restrict__ out, int n8) {
  int i = blockIdx.x * 256 + threadIdx.x;
  if (i >= n8) return;
  const fx4* p = (const fx4*)in;
  fx4 a = p[2 * i], b = p[2 * i + 1];
  h8 h;
  h[0] = (_Float16)a[0]; h[1] = (_Float16)a[1]; h[2] = (_Float16)a[2]; h[3] = (_Float16)a[3];
  h[4] = (_Float16)b[0]; h[5] = (_Float16)b[1]; h[6] = (_Float16)b[2]; h[7] = (_Float16)b[3];
  ((h8*)out)[i] = h;
}

// w[K][N] f32 -> wt[N][K] f16 (64x64 LDS tile transpose)
__global__ void wtrans_kernel(const float* __restrict__ w, _Float16* __restrict__ wt, int K, int N) {
  __shared__ float t[64][65];
  int n0 = blockIdx.x * 64, k0 = blockIdx.y * 64;
#pragma unroll
  for (int it = 0; it < 16; ++it) {
    int idx = it * 256 + threadIdx.x;
    int r = idx >> 6, c = idx & 63;
    t[r][c] = w[(size_t)(k0 + r) * N + n0 + c];
  }
  __syncthreads();
#pragma unroll
  for (int it = 0; it < 16; ++it) {
    int idx = it * 256 + threadIdx.x;
    int r = idx >> 6, c = idx & 63;
    wt[(size_t)(n0 + r) * K + k0 + c] = (_Float16)t[c][r];
  }
}

// V part of fused KV buffer -> Vt[b*4+g][128 d][512 s]
__global__ void vtrans_kernel(const _Float16* __restrict__ kv, _Float16* __restrict__ vt) {
  __shared__ _Float16 t[64][72];
  int st = blockIdx.x, dt = blockIdx.y, bg = blockIdx.z;
  int b = bg >> 2, g = bg & 3;
  const _Float16* src = kv + ((size_t)(b * NS + st * 64)) * NKV + NKD + g * NHD + dt * 64;
#pragma unroll
  for (int it = 0; it < 2; ++it) {
    int idx = it * 256 + threadIdx.x;  // 512 h8 chunks = 64x64 tile
    int r = idx >> 3, c = (idx & 7) * 8;
    *(h8*)&t[r][c] = *(const h8*)(src + (size_t)r * NKV + c);
  }
  __syncthreads();
  _Float16* dst = vt + ((size_t)bg * NHD + dt * 64) * NS + st * 64;
#pragma unroll
  for (int it = 0; it < 2; ++it) {
    int idx = it * 256 + threadIdx.x;
    int r = idx >> 3, c = (idx & 7) * 8;  // r = d within tile, c = kv cols
    h8 o;
#pragma unroll
    for (int e = 0; e < 8; ++e) o[e] = t[c + e][r];
    *(h8*)(dst + (size_t)r * NS + c) = o;
  }
}

__global__ void rope_tables_kernel(float* __restrict__ cosT, float* __restrict__ sinT) {
  int i = blockIdx.x * 256 + threadIdx.x;  // 512*64 total
  int s = i >> 6, f = i & 63;
  float inv = exp2f(-(float)f * (13.287712379549449f / 64.0f));
  float a = (float)s * inv;
  cosT[i] = cosf(a);
  sinT[i] = sinf(a);
}

// per (row, head): RMSNorm over 128, RoPE, *outScale, in-place f16
__global__ void norm_rope_kernel(_Float16* __restrict__ X, const float* __restrict__ scale,
                                 const float* __restrict__ cosT, const float* __restrict__ sinT,
                                 int hshift, int rowStride, float outScale) {
  int wid = threadIdx.x >> 6, lane = threadIdx.x & 63;
  int task = blockIdx.x * 4 + wid;
  int row = task >> hshift;
  int head = task & ((1 << hshift) - 1);
  _Float16* p = X + (size_t)row * rowStride + head * NHD;
  float x1 = (float)p[lane], x2 = (float)p[lane + 64];
  float ss = x1 * x1 + x2 * x2;
#pragma unroll
  for (int m = 1; m < 64; m <<= 1) ss += __shfl_xor(ss, m, 64);
  float rn = rsqrtf(ss * (1.0f / 128.0f) + 1e-6f);
  int s = row & (NS - 1);
  float c = cosT[s * 64 + lane], sn = sinT[s * 64 + lane];
  float n1 = x1 * rn * scale[lane], n2 = x2 * rn * scale[64 + lane];
  p[lane] = (_Float16)((n1 * c - n2 * sn) * outScale);
  p[lane + 64] = (_Float16)((n1 * sn + n2 * c) * outScale);
}

__device__ __forceinline__ void st_out(float* p, float v) { *p = v; }
__device__ __forceinline__ void st_out(_Float16* p, float v) { *p = (_Float16)v; }

// ---------------- GEMM 128x128 (2-phase) — used for the KV projection ----------------

template <typename OT>
__global__ __launch_bounds__(256, 3) void gemm_bt_kernel(
    const _Float16* __restrict__ A, const _Float16* __restrict__ Bt,
    const float* __restrict__ bias, OT* __restrict__ C, int N, int K) {
  __shared__ alignas(16) _Float16 As[128 * 64];
  __shared__ alignas(16) _Float16 Bs[128 * 64];
  const int tid = threadIdx.x;
  const int lane = tid & 63, wid = tid >> 6;
  const int wr = wid >> 1, wc = wid & 1;
  const int la = lane & 15, lb = (lane >> 4) * 8;
  const int bm = blockIdx.y * 128, bn = blockIdx.x * 128;

  fx4 acc[4][4] = {};

  for (int kt = 0; kt < K; kt += 64) {
    const _Float16* Ag = A + (size_t)bm * K + kt;
    const _Float16* Bg = Bt + (size_t)bn * K + kt;
#pragma unroll
    for (int it = 0; it < 4; ++it) {
      int cb = it * 256 + wid * 64;  // wave-uniform chunk base
      int ca = cb + lane;
      int r = ca >> 3, cc = ca & 7;
      gload16(Ag + (size_t)r * K + cc * 8, &As[cb * 8]);
      gload16(Bg + (size_t)r * K + cc * 8, &Bs[cb * 8]);
    }
    __syncthreads();
#pragma unroll
    for (int kk = 0; kk < 2; ++kk) {
      h8 af[4], bf[4];
#pragma unroll
      for (int m = 0; m < 4; ++m)
        af[m] = *(const h8*)&As[(wr * 64 + m * 16 + la) * 64 + kk * 32 + lb];
#pragma unroll
      for (int n = 0; n < 4; ++n)
        bf[n] = *(const h8*)&Bs[(wc * 64 + n * 16 + la) * 64 + kk * 32 + lb];
#pragma unroll
      for (int m = 0; m < 4; ++m)
#pragma unroll
        for (int n = 0; n < 4; ++n)
          acc[m][n] = __builtin_amdgcn_mfma_f32_16x16x32_f16(af[m], bf[n], acc[m][n], 0, 0, 0);
    }
    __syncthreads();
  }
#pragma unroll
  for (int m = 0; m < 4; ++m) {
    int row0 = bm + wr * 64 + m * 16 + (lane >> 4) * 4;
#pragma unroll
    for (int n = 0; n < 4; ++n) {
      int col = bn + wc * 64 + n * 16 + la;
      float bvv = bias[col];
#pragma unroll
      for (int r = 0; r < 4; ++r)
        st_out(&C[(size_t)(row0 + r) * N + col], acc[m][n][r] + bvv);
    }
  }
}

// ---------------- GEMM 256x256 8-phase (T2+T3+T4+T5) — big projections ----------------
// 512 threads = 8 waves (2M x 4N), BK=64, LDS 2x(32K A + 32K B) = 128 KB.
// Counted vmcnt(8): next K-tile's 8 loads/thread stay in flight across raw
// s_barrier. 4 phases per K-tile: 12 ds_read_b128 -> lgkmcnt(0) -> 16 MFMA.
// XOR-chunk swizzle (c ^= row&7) on both stage-source and ds_read (rule 21).
// Buffer safety: buf[cur^1] is re-staged only at top of iter kt+1, after the
// trailing barrier that seals all lgkmcnt(0)-completed reads of it.

template <typename OT>
__global__ __launch_bounds__(512, 2) void gemm256_kernel(
    const _Float16* __restrict__ A, const _Float16* __restrict__ Bt,
    const float* __restrict__ bias, OT* __restrict__ C, int N, int K) {
  __shared__ alignas(16) _Float16 As[2][256 * 64];
  __shared__ alignas(16) _Float16 Bs[2][256 * 64];
  const int tid = threadIdx.x;
  const int lane = tid & 63, w = tid >> 6;
  const int wr = w >> 2, wc = w & 3;  // 2 x 4 wave grid
  const int la = lane & 15, lq = lane >> 4;
  // XCD-grouped swizzle: grid=256, each XCD owns 32 contiguous logical ids
  // -> 4 A-panels (4MB) resident in its L2, B streamed (L3-cached).
  const int lin = (blockIdx.x & 7) * 32 + (blockIdx.x >> 3);
  const int nbx = N >> 8;
  const int by = lin / nbx, bx = lin % nbx;
  const int bm = by * 256, bn = bx * 256;
  const int NT = K >> 6;

  fx4 acc[8][4] = {};

  auto stage = [&](int buf, int kt) {
    const _Float16* Ag = A + (size_t)bm * K + kt * 64;
    const _Float16* Bg = Bt + (size_t)bn * K + kt * 64;
#pragma unroll
    for (int it = 0; it < 4; ++it) {
      int cb = it * 512 + w * 64;
      int s = cb + lane;
      int r = s >> 3, c = s & 7;
      int srcoff = r * K + ((c ^ (r & 7)) << 3);
      gload16(Ag + srcoff, &As[buf][cb * 8]);
      gload16(Bg + srcoff, &Bs[buf][cb * 8]);
    }
  };

  stage(0, 0);
  for (int kt = 0; kt < NT; ++kt) {
    const int cur = kt & 1;
    if (kt + 1 < NT) {
      stage(cur ^ 1, kt + 1);
      asm volatile("s_waitcnt vmcnt(8)" ::: "memory");  // tile kt landed; kt+1 in flight
    } else {
      asm volatile("s_waitcnt vmcnt(0)" ::: "memory");
    }
    __builtin_amdgcn_s_barrier();
    __builtin_amdgcn_sched_barrier(0);
#pragma unroll
    for (int q = 0; q < 4; ++q) {
      h8 af[2][2], bf[4][2];
#pragma unroll
      for (int mi = 0; mi < 2; ++mi)
#pragma unroll
        for (int kk = 0; kk < 2; ++kk) {
          int row = wr * 128 + (q * 2 + mi) * 16 + la;
          int c = kk * 4 + lq;
          af[mi][kk] = *(const h8*)&As[cur][row * 64 + ((c ^ (row & 7)) << 3)];
        }
#pragma unroll
      for (int ni = 0; ni < 4; ++ni)
#pragma unroll
        for (int kk = 0; kk < 2; ++kk) {
          int row = wc * 64 + ni * 16 + la;
          int c = kk * 4 + lq;
          bf[ni][kk] = *(const h8*)&Bs[cur][row * 64 + ((c ^ (row & 7)) << 3)];
        }
      asm volatile("s_waitcnt lgkmcnt(0)" ::: "memory");
      __builtin_amdgcn_sched_barrier(0);
      __builtin_amdgcn_s_setprio(1);
#pragma unroll
      for (int mi = 0; mi < 2; ++mi)
#pragma unroll
        for (int ni = 0; ni < 4; ++ni)
#pragma unroll
          for (int kk = 0; kk < 2; ++kk)
            acc[q * 2 + mi][ni] = __builtin_amdgcn_mfma_f32_16x16x32_f16(
                af[mi][kk], bf[ni][kk], acc[q * 2 + mi][ni], 0, 0, 0);
      __builtin_amdgcn_s_setprio(0);
      __builtin_amdgcn_sched_barrier(0);
      __builtin_amdgcn_s_barrier();  // phase boundary (trailing one seals buf reads)
    }
  }
  // epilogue
#pragma unroll
  for (int mi = 0; mi < 8; ++mi) {
    int row0 = bm + wr * 128 + mi * 16 + lq * 4;
#pragma unroll
    for (int ni = 0; ni < 4; ++ni) {
      int col = bn + wc * 64 + ni * 16 + la;
      float bvv = bias[col];
#pragma unroll
      for (int r = 0; r < 4; ++r)
        st_out(&C[(size_t)(row0 + r) * N + col], acc[mi][ni][r] + bvv);
    }
  }
}

// ---------------- flash attention ----------------
// 512 blocks x 512 threads. Block = (q-tile pair {j,15-j}, group g, batch b):
// processes all 4 heads of the group; wave = (head, 16 q-rows). Each block does
// exactly 9 kt-tiles total (causal-balanced). K/V LDS double-buffered, one
// barrier per tile: stage(next) issued right after barrier, compute overlaps.
// XCD-chunk swizzle: each XCD covers 2 batches -> 2MB KV set fits its L2.

__global__ __launch_bounds__(512, 4) void attn_kernel(
    const _Float16* __restrict__ Q, const _Float16* __restrict__ KV,
    const _Float16* __restrict__ Vt, _Float16* __restrict__ ctx) {
  __shared__ alignas(16) _Float16 Ks[2][64 * 128];   // [kv][d], swizzled
  __shared__ alignas(16) _Float16 Vs[2][128 * 64];   // [d][kv], swizzled
  __shared__ alignas(16) _Float16 Ps[8][16 * 64];    // per-wave P, swizzled

  const int bid = blockIdx.x;
  const int logical = (bid & 7) * 64 + (bid >> 3);   // XCD chunk swizzle (512 = 8*64)
  const int b = logical >> 5;
  const int g = (logical >> 3) & 3;
  const int jp = logical & 7;
  const int j1 = jp, j2 = 15 - jp;

  const int tid = threadIdx.x;
  const int lane = tid & 63, w = tid >> 6;
  const int la = lane & 15, lq = lane >> 4;
  const int h = g * 4 + (w & 3);
  const int rh = w >> 2;

  const _Float16* Vg = Vt + (size_t)(b * NG + g) * NHD * NS;

  auto stage = [&](int buf, int kt) {
    const _Float16* Kg = KV + ((size_t)(b * NS + kt * 64)) * NKV + g * NHD;
#pragma unroll
    for (int it = 0; it < 2; ++it) {
      int cb = it * 512 + w * 64;
      int s = cb + lane;
      int rr = s >> 4, c = s & 15;
      gload16(Kg + (size_t)rr * NKV + ((c ^ (rr & 7)) * 8), &Ks[buf][cb * 8]);
    }
#pragma unroll
    for (int it = 0; it < 2; ++it) {
      int cb = it * 512 + w * 64;
      int s = cb + lane;
      int rr = s >> 3, c = s & 7;
      gload16(Vg + (size_t)rr * NS + kt * 64 + ((c ^ (rr & 7)) * 8), &Vs[buf][cb * 8]);
    }
  };

  const int nt1 = ((j1 * 32 + 31) >> 6) + 1;
  const int nt2 = ((j2 * 32 + 31) >> 6) + 1;
  const int ntotal = nt1 + nt2;  // == 9

  h8 qf[4];
  fx4 oacc[8];
  float mrun[4], lrun[4];

  stage(0, 0);
  int cur = 0;
  for (int t = 0; t < ntotal; ++t) {
    const bool inA = t < nt1;
    const int j = inA ? j1 : j2;
    const int kt = inA ? t : t - nt1;
    const int ntj = inA ? nt1 : nt2;
    __syncthreads();  // drains vmcnt(0): buf[cur] staged; all waves done with buf[cur^1]
    if (t + 1 < ntotal) {
      int nkt = (t + 1 < nt1) ? (t + 1) : (t + 1 - nt1);
      stage(cur ^ 1, nkt);
    }
    if (kt == 0) {  // new q-tile: load Q frags, reset online-softmax state
      const _Float16* Qg = Q + ((size_t)(b * NS + j * 32 + rh * 16 + la)) * ND + h * NHD + lq * 8;
#pragma unroll
      for (int kc = 0; kc < 4; ++kc) qf[kc] = *(const h8*)(Qg + kc * 32);
#pragma unroll
      for (int f = 0; f < 8; ++f) oacc[f] = fx4{0.f, 0.f, 0.f, 0.f};
#pragma unroll
      for (int r = 0; r < 4; ++r) { mrun[r] = -1e30f; lrun[r] = 0.f; }
    }

    // QK^T: 16 q-rows x 64 kv
    fx4 sc[4] = {};
    __builtin_amdgcn_s_setprio(1);
#pragma unroll
    for (int n = 0; n < 4; ++n) {
      int row = n * 16 + la;
#pragma unroll
      for (int kc = 0; kc < 4; ++kc) {
        h8 bk = *(const h8*)&Ks[cur][row * 128 + (((kc * 4 + lq) ^ (la & 7)) * 8)];
        sc[n] = __builtin_amdgcn_mfma_f32_16x16x32_f16(qf[kc], bk, sc[n], 0, 0, 0);
      }
    }
    __builtin_amdgcn_s_setprio(0);

    const int qrow0 = j * 32 + rh * 16 + lq * 4;
    const bool maskT = (kt == ntj - 1);  // only the diagonal tile needs masking
    float pv[4][4];
    float rm[4] = {-1e30f, -1e30f, -1e30f, -1e30f};
#pragma unroll
    for (int n = 0; n < 4; ++n) {
      int kv = kt * 64 + n * 16 + la;
#pragma unroll
      for (int r = 0; r < 4; ++r) {
        float sv = sc[n][r] * HEAD_SCALE;
        sv = (maskT && kv > qrow0 + r) ? -1e30f : sv;
        pv[n][r] = sv;
        rm[r] = fmaxf(rm[r], sv);
      }
    }
#pragma unroll
    for (int r = 0; r < 4; ++r) {
#pragma unroll
      for (int m = 1; m < 16; m <<= 1) rm[r] = fmaxf(rm[r], __shfl_xor(rm[r], m, 64));
      float mn = fmaxf(mrun[r], rm[r]);
      float corr = __expf(mrun[r] - mn);
      mrun[r] = mn;
      lrun[r] *= corr;
#pragma unroll
      for (int f = 0; f < 8; ++f) oacc[f][r] *= corr;
    }
    float rs[4] = {0.f, 0.f, 0.f, 0.f};
#pragma unroll
    for (int n = 0; n < 4; ++n)
#pragma unroll
      for (int r = 0; r < 4; ++r) {
        float e = __expf(pv[n][r] - mrun[r]);
        pv[n][r] = e;
        rs[r] += e;
      }
#pragma unroll
    for (int r = 0; r < 4; ++r) {
#pragma unroll
      for (int m = 1; m < 16; m <<= 1) rs[r] += __shfl_xor(rs[r], m, 64);
      lrun[r] += rs[r];
    }

    // P (C-layout) -> LDS (swizzled) -> reload in A-layout (wave-local)
#pragma unroll
    for (int n = 0; n < 4; ++n)
#pragma unroll
      for (int r = 0; r < 4; ++r) {
        int row = lq * 4 + r;
        int chsw = (n * 2 + (la >> 3)) ^ (row & 7);
        Ps[w][row * 64 + chsw * 8 + (la & 7)] = (_Float16)pv[n][r];
      }
    asm volatile("s_waitcnt lgkmcnt(0)" ::: "memory");
    __builtin_amdgcn_sched_barrier(0);
    h8 pf[2];
#pragma unroll
    for (int ks = 0; ks < 2; ++ks)
      pf[ks] = *(const h8*)&Ps[w][la * 64 + (((ks * 4 + lq) ^ (la & 7)) * 8)];

    // PV: oacc[16 rows][128 d]
    __builtin_amdgcn_s_setprio(1);
#pragma unroll
    for (int f = 0; f < 8; ++f) {
      int row = f * 16 + la;
#pragma unroll
      for (int ks = 0; ks < 2; ++ks) {
        h8 bv = *(const h8*)&Vs[cur][row * 64 + (((ks * 4 + lq) ^ (la & 7)) * 8)];
        oacc[f] = __builtin_amdgcn_mfma_f32_16x16x32_f16(pf[ks], bv, oacc[f], 0, 0, 0);
      }
    }
    __builtin_amdgcn_s_setprio(0);

    if (maskT) {  // last tile of this q-tile: write output
      _Float16* Cg = ctx + ((size_t)(b * NS + qrow0)) * ND + h * NHD + la;
      float inv_l[4];
#pragma unroll
      for (int r = 0; r < 4; ++r) inv_l[r] = 1.0f / lrun[r];
#pragma unroll
      for (int f = 0; f < 8; ++f)
#pragma unroll
        for (int r = 0; r < 4; ++r)
          Cg[(size_t)r * ND + f * 16] = (_Float16)(oacc[f][r] * inv_l[r]);
    }
    cur ^= 1;
  }
}

// ---------------- launch ----------------

extern "C" void kernel_launch(void* const* d_in, const int* in_sizes, int n_in,
                              void* d_out, int out_size, void* d_ws, size_t ws_size,
                              hipStream_t stream) {
  (void)in_sizes; (void)n_in; (void)out_size; (void)ws_size;
  const float* x = (const float*)d_in[0];
  const float* wq = (const float*)d_in[1];
  const float* bq = (const float*)d_in[2];
  const float* wk = (const float*)d_in[3];
  const float* bk = (const float*)d_in[4];
  const float* wv = (const float*)d_in[5];
  const float* bv = (const float*)d_in[6];
  const float* wo = (const float*)d_in[7];
  const float* bo = (const float*)d_in[8];
  const float* qns = (const float*)d_in[9];
  const float* kns = (const float*)d_in[10];

  char* ws = (char*)d_ws;
  size_t off = 0;
  _Float16* xh = (_Float16*)(ws + off); off += (size_t)NM * ND * 2;       // 32MB
  _Float16* wqt = (_Float16*)(ws + off); off += (size_t)ND * ND * 2;      // 8MB
  _Float16* wkvt = (_Float16*)(ws + off); off += (size_t)NKV * ND * 2;    // 4MB
  _Float16* wot = (_Float16*)(ws + off); off += (size_t)ND * ND * 2;      // 8MB
  _Float16* Qb = (_Float16*)(ws + off); off += (size_t)NM * ND * 2;       // 32MB
  _Float16* KVbuf = (_Float16*)(ws + off); off += (size_t)NM * NKV * 2;   // 16MB
  float* cosT = (float*)(ws + off); off += (size_t)NS * 64 * 4;
  float* sinT = (float*)(ws + off); off += (size_t)NS * 64 * 4;
  float* bkv = (float*)(ws + off); off += (size_t)NKV * 4;
  _Float16* ctx = xh;            // xh dead after KV GEMM; reuse
  _Float16* Vtg = wqt;           // wqt dead after Q GEMM; reuse (needs 8MB)

  cvt_x_kernel<<<NM * ND / 8 / 256, 256, 0, stream>>>(x, xh, NM * ND / 8);
  wtrans_kernel<<<dim3(ND / 64, ND / 64), 256, 0, stream>>>(wq, wqt, ND, ND);
  wtrans_kernel<<<dim3(NKD / 64, ND / 64), 256, 0, stream>>>(wk, wkvt, ND, NKD);
  wtrans_kernel<<<dim3(NKD / 64, ND / 64), 256, 0, stream>>>(wv, wkvt + (size_t)NKD * ND, ND, NKD);
  wtrans_kernel<<<dim3(ND / 64, ND / 64), 256, 0, stream>>>(wo, wot, ND, ND);
  rope_tables_kernel<<<NS * 64 / 256, 256, 0, stream>>>(cosT, sinT);
  hipMemcpyAsync(bkv, bk, NKD * sizeof(float), hipMemcpyDeviceToDevice, stream);
  hipMemcpyAsync(bkv + NKD, bv, NKD * sizeof(float), hipMemcpyDeviceToDevice, stream);

  gemm256_kernel<_Float16><<<dim3(256), dim3(512), 0, stream>>>(xh, wqt, bq, Qb, ND, ND);
  gemm_bt_kernel<_Float16><<<dim3(NKV / 128, NM / 128), 256, 0, stream>>>(xh, wkvt, bkv, KVbuf, NKV, ND);

  norm_rope_kernel<<<NM * NH / 4, 256, 0, stream>>>(Qb, qns, cosT, sinT, 4, ND, HEAD_SCALE);
  norm_rope_kernel<<<NM * NG / 4, 256, 0, stream>>>(KVbuf, kns, cosT, sinT, 2, NKV, 1.0f);

  vtrans_kernel<<<dim3(NS / 64, NHD / 64, NB * NG), 256, 0, stream>>>(KVbuf, Vtg);

  attn_kernel<<<dim3(512), dim3(512), 0, stream>>>(Qb, KVbuf, Vtg, ctx);

  gemm256_kernel<float><<<dim3(256), dim3(512), 0, stream>>>(ctx, wot, bo, (float*)d_out, ND, ND);
}

// Round 5
// 305.931 us; speedup vs baseline: 1.8367x; 1.0521x over previous
//
#include <hip/hip_runtime.h>

// Problem constants
#define NB 16
#define NS 512
#define ND 2048
#define NH 16
#define NG 4
#define NHD 128
#define NM (NB * NS)      // 8192 rows (b*s)
#define NKD (NG * NHD)    // 512
#define NKV 1024          // fused K|V row width
#define HEAD_SCALE 0.08838834764831845f

typedef _Float16 h8 __attribute__((ext_vector_type(8)));
typedef float fx4 __attribute__((ext_vector_type(4)));

// global -> LDS direct copy, 16B per lane. LDS dest is wave-uniform base + lane*16.
__device__ __forceinline__ void gload16(const void* g, void* l) {
  __builtin_amdgcn_global_load_lds(
      (__attribute__((address_space(1))) void*)(unsigned long long)g,
      (__attribute__((address_space(3))) void*)(unsigned long long)l,
      16, 0, 0);
}

// ---------------- prep kernels ----------------

__global__ void cvt_x_kernel(const float* __restrict__ in, _Float16* __restrict__ out, int n8) {
  int i = blockIdx.x * 256 + threadIdx.x;
  if (i >= n8) return;
  const fx4* p = (const fx4*)in;
  fx4 a = p[2 * i], b = p[2 * i + 1];
  h8 h;
  h[0] = (_Float16)a[0]; h[1] = (_Float16)a[1]; h[2] = (_Float16)a[2]; h[3] = (_Float16)a[3];
  h[4] = (_Float16)b[0]; h[5] = (_Float16)b[1]; h[6] = (_Float16)b[2]; h[7] = (_Float16)b[3];
  ((h8*)out)[i] = h;
}

// w[K][N] f32 -> wt[N][K] f16 (64x64 LDS tile transpose)
__global__ void wtrans_kernel(const float* __restrict__ w, _Float16* __restrict__ wt, int K, int N) {
  __shared__ float t[64][65];
  int n0 = blockIdx.x * 64, k0 = blockIdx.y * 64;
#pragma unroll
  for (int it = 0; it < 16; ++it) {
    int idx = it * 256 + threadIdx.x;
    int r = idx >> 6, c = idx & 63;
    t[r][c] = w[(size_t)(k0 + r) * N + n0 + c];
  }
  __syncthreads();
#pragma unroll
  for (int it = 0; it < 16; ++it) {
    int idx = it * 256 + threadIdx.x;
    int r = idx >> 6, c = idx & 63;
    wt[(size_t)(n0 + r) * K + k0 + c] = (_Float16)t[c][r];
  }
}

// V part of fused KV buffer -> Vt[b*4+g][128 d][512 s]
__global__ void vtrans_kernel(const _Float16* __restrict__ kv, _Float16* __restrict__ vt) {
  __shared__ _Float16 t[64][72];
  int st = blockIdx.x, dt = blockIdx.y, bg = blockIdx.z;
  int b = bg >> 2, g = bg & 3;
  const _Float16* src = kv + ((size_t)(b * NS + st * 64)) * NKV + NKD + g * NHD + dt * 64;
#pragma unroll
  for (int it = 0; it < 2; ++it) {
    int idx = it * 256 + threadIdx.x;  // 512 h8 chunks = 64x64 tile
    int r = idx >> 3, c = (idx & 7) * 8;
    *(h8*)&t[r][c] = *(const h8*)(src + (size_t)r * NKV + c);
  }
  __syncthreads();
  _Float16* dst = vt + ((size_t)bg * NHD + dt * 64) * NS + st * 64;
#pragma unroll
  for (int it = 0; it < 2; ++it) {
    int idx = it * 256 + threadIdx.x;
    int r = idx >> 3, c = (idx & 7) * 8;  // r = d within tile, c = kv cols
    h8 o;
#pragma unroll
    for (int e = 0; e < 8; ++e) o[e] = t[c + e][r];
    *(h8*)(dst + (size_t)r * NS + c) = o;
  }
}

__global__ void rope_tables_kernel(float* __restrict__ cosT, float* __restrict__ sinT) {
  int i = blockIdx.x * 256 + threadIdx.x;  // 512*64 total
  int s = i >> 6, f = i & 63;
  float inv = exp2f(-(float)f * (13.287712379549449f / 64.0f));
  float a = (float)s * inv;
  cosT[i] = cosf(a);
  sinT[i] = sinf(a);
}

// per (row, head): RMSNorm over 128, RoPE, *outScale, in-place f16
__global__ void norm_rope_kernel(_Float16* __restrict__ X, const float* __restrict__ scale,
                                 const float* __restrict__ cosT, const float* __restrict__ sinT,
                                 int hshift, int rowStride, float outScale) {
  int wid = threadIdx.x >> 6, lane = threadIdx.x & 63;
  int task = blockIdx.x * 4 + wid;
  int row = task >> hshift;
  int head = task & ((1 << hshift) - 1);
  _Float16* p = X + (size_t)row * rowStride + head * NHD;
  float x1 = (float)p[lane], x2 = (float)p[lane + 64];
  float ss = x1 * x1 + x2 * x2;
#pragma unroll
  for (int m = 1; m < 64; m <<= 1) ss += __shfl_xor(ss, m, 64);
  float rn = rsqrtf(ss * (1.0f / 128.0f) + 1e-6f);
  int s = row & (NS - 1);
  float c = cosT[s * 64 + lane], sn = sinT[s * 64 + lane];
  float n1 = x1 * rn * scale[lane], n2 = x2 * rn * scale[64 + lane];
  p[lane] = (_Float16)((n1 * c - n2 * sn) * outScale);
  p[lane + 64] = (_Float16)((n1 * sn + n2 * c) * outScale);
}

__device__ __forceinline__ void st_out(float* p, float v) { *p = v; }
__device__ __forceinline__ void st_out(_Float16* p, float v) { *p = (_Float16)v; }

// ---------------- GEMM 128x128 (2-phase) — used for the KV projection ----------------

template <typename OT>
__global__ __launch_bounds__(256, 3) void gemm_bt_kernel(
    const _Float16* __restrict__ A, const _Float16* __restrict__ Bt,
    const float* __restrict__ bias, OT* __restrict__ C, int N, int K) {
  __shared__ alignas(16) _Float16 As[128 * 64];
  __shared__ alignas(16) _Float16 Bs[128 * 64];
  const int tid = threadIdx.x;
  const int lane = tid & 63, wid = tid >> 6;
  const int wr = wid >> 1, wc = wid & 1;
  const int la = lane & 15, lb = (lane >> 4) * 8;
  const int bm = blockIdx.y * 128, bn = blockIdx.x * 128;

  fx4 acc[4][4] = {};

  for (int kt = 0; kt < K; kt += 64) {
    const _Float16* Ag = A + (size_t)bm * K + kt;
    const _Float16* Bg = Bt + (size_t)bn * K + kt;
#pragma unroll
    for (int it = 0; it < 4; ++it) {
      int cb = it * 256 + wid * 64;  // wave-uniform chunk base
      int ca = cb + lane;
      int r = ca >> 3, cc = ca & 7;
      gload16(Ag + (size_t)r * K + cc * 8, &As[cb * 8]);
      gload16(Bg + (size_t)r * K + cc * 8, &Bs[cb * 8]);
    }
    __syncthreads();
#pragma unroll
    for (int kk = 0; kk < 2; ++kk) {
      h8 af[4], bf[4];
#pragma unroll
      for (int m = 0; m < 4; ++m)
        af[m] = *(const h8*)&As[(wr * 64 + m * 16 + la) * 64 + kk * 32 + lb];
#pragma unroll
      for (int n = 0; n < 4; ++n)
        bf[n] = *(const h8*)&Bs[(wc * 64 + n * 16 + la) * 64 + kk * 32 + lb];
#pragma unroll
      for (int m = 0; m < 4; ++m)
#pragma unroll
        for (int n = 0; n < 4; ++n)
          acc[m][n] = __builtin_amdgcn_mfma_f32_16x16x32_f16(af[m], bf[n], acc[m][n], 0, 0, 0);
    }
    __syncthreads();
  }
#pragma unroll
  for (int m = 0; m < 4; ++m) {
    int row0 = bm + wr * 64 + m * 16 + (lane >> 4) * 4;
#pragma unroll
    for (int n = 0; n < 4; ++n) {
      int col = bn + wc * 64 + n * 16 + la;
      float bvv = bias[col];
#pragma unroll
      for (int r = 0; r < 4; ++r)
        st_out(&C[(size_t)(row0 + r) * N + col], acc[m][n][r] + bvv);
    }
  }
}

// ---------------- GEMM 256x256 8-phase (T2+T3+T4+T5) — big projections ----------------
// 512 threads = 8 waves (2M x 4N), BK=64, LDS 2x(32K A + 32K B) = 128 KB.
// Counted vmcnt(8): next K-tile's 8 loads stay in flight across raw s_barrier.
// B-fragments hoisted: loaded ONCE per K-tile (8 ds_read_b128), phases carry
// only 4 A-reads + 16 MFMA each -> LDS read traffic 192KB/K-tile (was 384KB).
// XOR-chunk swizzle (c ^= row&7) on both stage-source and ds_read (rule 21).

template <typename OT>
__global__ __launch_bounds__(512, 2) void gemm256_kernel(
    const _Float16* __restrict__ A, const _Float16* __restrict__ Bt,
    const float* __restrict__ bias, OT* __restrict__ C, int N, int K) {
  __shared__ alignas(16) _Float16 As[2][256 * 64];
  __shared__ alignas(16) _Float16 Bs[2][256 * 64];
  const int tid = threadIdx.x;
  const int lane = tid & 63, w = tid >> 6;
  const int wr = w >> 2, wc = w & 3;  // 2 x 4 wave grid
  const int la = lane & 15, lq = lane >> 4;
  const int lin = (blockIdx.x & 7) * 32 + (blockIdx.x >> 3);
  const int nbx = N >> 8;
  const int by = lin / nbx, bx = lin % nbx;
  const int bm = by * 256, bn = bx * 256;
  const int NT = K >> 6;

  fx4 acc[8][4] = {};

  auto stage = [&](int buf, int kt) {
    const _Float16* Ag = A + (size_t)bm * K + kt * 64;
    const _Float16* Bg = Bt + (size_t)bn * K + kt * 64;
#pragma unroll
    for (int it = 0; it < 4; ++it) {
      int cb = it * 512 + w * 64;
      int s = cb + lane;
      int r = s >> 3, c = s & 7;
      int srcoff = r * K + ((c ^ (r & 7)) << 3);
      gload16(Ag + srcoff, &As[buf][cb * 8]);
      gload16(Bg + srcoff, &Bs[buf][cb * 8]);
    }
  };

  stage(0, 0);
  for (int kt = 0; kt < NT; ++kt) {
    const int cur = kt & 1;
    if (kt + 1 < NT) {
      stage(cur ^ 1, kt + 1);
      asm volatile("s_waitcnt vmcnt(8)" ::: "memory");  // tile kt landed; kt+1 in flight
    } else {
      asm volatile("s_waitcnt vmcnt(0)" ::: "memory");
    }
    __builtin_amdgcn_s_barrier();
    __builtin_amdgcn_sched_barrier(0);
    // B-fragments for the whole K-tile (used by all 4 phases)
    h8 bf[4][2];
#pragma unroll
    for (int ni = 0; ni < 4; ++ni)
#pragma unroll
      for (int kk = 0; kk < 2; ++kk) {
        int row = wc * 64 + ni * 16 + la;
        int c = kk * 4 + lq;
        bf[ni][kk] = *(const h8*)&Bs[cur][row * 64 + ((c ^ (row & 7)) << 3)];
      }
#pragma unroll
    for (int q = 0; q < 4; ++q) {
      h8 af[2][2];
#pragma unroll
      for (int mi = 0; mi < 2; ++mi)
#pragma unroll
        for (int kk = 0; kk < 2; ++kk) {
          int row = wr * 128 + (q * 2 + mi) * 16 + la;
          int c = kk * 4 + lq;
          af[mi][kk] = *(const h8*)&As[cur][row * 64 + ((c ^ (row & 7)) << 3)];
        }
      asm volatile("s_waitcnt lgkmcnt(0)" ::: "memory");
      __builtin_amdgcn_sched_barrier(0);
      __builtin_amdgcn_s_setprio(1);
#pragma unroll
      for (int mi = 0; mi < 2; ++mi)
#pragma unroll
        for (int ni = 0; ni < 4; ++ni)
#pragma unroll
          for (int kk = 0; kk < 2; ++kk)
            acc[q * 2 + mi][ni] = __builtin_amdgcn_mfma_f32_16x16x32_f16(
                af[mi][kk], bf[ni][kk], acc[q * 2 + mi][ni], 0, 0, 0);
      __builtin_amdgcn_s_setprio(0);
      __builtin_amdgcn_sched_barrier(0);
      __builtin_amdgcn_s_barrier();  // phase boundary (trailing one seals buf reads)
    }
  }
  // epilogue
#pragma unroll
  for (int mi = 0; mi < 8; ++mi) {
    int row0 = bm + wr * 128 + mi * 16 + lq * 4;
#pragma unroll
    for (int ni = 0; ni < 4; ++ni) {
      int col = bn + wc * 64 + ni * 16 + la;
      float bvv = bias[col];
#pragma unroll
      for (int r = 0; r < 4; ++r)
        st_out(&C[(size_t)(row0 + r) * N + col], acc[mi][ni][r] + bvv);
    }
  }
}

// ---------------- flash attention ----------------
// 512 blocks x 512 threads. Block = (q-tile pair {j,15-j}, group g, batch b):
// processes all 4 heads of the group; wave = (head, 16 q-rows). Each block does
// exactly 9 kt-tiles total (causal-balanced). K/V LDS double-buffered, one
// barrier per tile: stage(next) issued right after barrier, compute overlaps.
// XCD-chunk swizzle: each XCD covers 2 batches -> 2MB KV set fits its L2.

__global__ __launch_bounds__(512, 4) void attn_kernel(
    const _Float16* __restrict__ Q, const _Float16* __restrict__ KV,
    const _Float16* __restrict__ Vt, _Float16* __restrict__ ctx) {
  __shared__ alignas(16) _Float16 Ks[2][64 * 128];   // [kv][d], swizzled
  __shared__ alignas(16) _Float16 Vs[2][128 * 64];   // [d][kv], swizzled
  __shared__ alignas(16) _Float16 Ps[8][16 * 64];    // per-wave P, swizzled

  const int bid = blockIdx.x;
  const int logical = (bid & 7) * 64 + (bid >> 3);   // XCD chunk swizzle (512 = 8*64)
  const int b = logical >> 5;
  const int g = (logical >> 3) & 3;
  const int jp = logical & 7;
  const int j1 = jp, j2 = 15 - jp;

  const int tid = threadIdx.x;
  const int lane = tid & 63, w = tid >> 6;
  const int la = lane & 15, lq = lane >> 4;
  const int h = g * 4 + (w & 3);
  const int rh = w >> 2;

  const _Float16* Vg = Vt + (size_t)(b * NG + g) * NHD * NS;

  auto stage = [&](int buf, int kt) {
    const _Float16* Kg = KV + ((size_t)(b * NS + kt * 64)) * NKV + g * NHD;
#pragma unroll
    for (int it = 0; it < 2; ++it) {
      int cb = it * 512 + w * 64;
      int s = cb + lane;
      int rr = s >> 4, c = s & 15;
      gload16(Kg + (size_t)rr * NKV + ((c ^ (rr & 7)) * 8), &Ks[buf][cb * 8]);
    }
#pragma unroll
    for (int it = 0; it < 2; ++it) {
      int cb = it * 512 + w * 64;
      int s = cb + lane;
      int rr = s >> 3, c = s & 7;
      gload16(Vg + (size_t)rr * NS + kt * 64 + ((c ^ (rr & 7)) * 8), &Vs[buf][cb * 8]);
    }
  };

  const int nt1 = ((j1 * 32 + 31) >> 6) + 1;
  const int nt2 = ((j2 * 32 + 31) >> 6) + 1;
  const int ntotal = nt1 + nt2;  // == 9

  h8 qf[4];
  fx4 oacc[8];
  float mrun[4], lrun[4];

  stage(0, 0);
  int cur = 0;
  for (int t = 0; t < ntotal; ++t) {
    const bool inA = t < nt1;
    const int j = inA ? j1 : j2;
    const int kt = inA ? t : t - nt1;
    const int ntj = inA ? nt1 : nt2;
    __syncthreads();  // drains vmcnt(0): buf[cur] staged; all waves done with buf[cur^1]
    if (t + 1 < ntotal) {
      int nkt = (t + 1 < nt1) ? (t + 1) : (t + 1 - nt1);
      stage(cur ^ 1, nkt);
    }
    if (kt == 0) {  // new q-tile: load Q frags, reset online-softmax state
      const _Float16* Qg = Q + ((size_t)(b * NS + j * 32 + rh * 16 + la)) * ND + h * NHD + lq * 8;
#pragma unroll
      for (int kc = 0; kc < 4; ++kc) qf[kc] = *(const h8*)(Qg + kc * 32);
#pragma unroll
      for (int f = 0; f < 8; ++f) oacc[f] = fx4{0.f, 0.f, 0.f, 0.f};
#pragma unroll
      for (int r = 0; r < 4; ++r) { mrun[r] = -1e30f; lrun[r] = 0.f; }
    }

    // QK^T: 16 q-rows x 64 kv
    fx4 sc[4] = {};
    __builtin_amdgcn_s_setprio(1);
#pragma unroll
    for (int n = 0; n < 4; ++n) {
      int row = n * 16 + la;
#pragma unroll
      for (int kc = 0; kc < 4; ++kc) {
        h8 bk = *(const h8*)&Ks[cur][row * 128 + (((kc * 4 + lq) ^ (la & 7)) * 8)];
        sc[n] = __builtin_amdgcn_mfma_f32_16x16x32_f16(qf[kc], bk, sc[n], 0, 0, 0);
      }
    }
    __builtin_amdgcn_s_setprio(0);

    const int qrow0 = j * 32 + rh * 16 + lq * 4;
    const bool maskT = (kt == ntj - 1);  // only the diagonal tile needs masking
    float pv[4][4];
    float rm[4] = {-1e30f, -1e30f, -1e30f, -1e30f};
#pragma unroll
    for (int n = 0; n < 4; ++n) {
      int kv = kt * 64 + n * 16 + la;
#pragma unroll
      for (int r = 0; r < 4; ++r) {
        float sv = sc[n][r] * HEAD_SCALE;
        sv = (maskT && kv > qrow0 + r) ? -1e30f : sv;
        pv[n][r] = sv;
        rm[r] = fmaxf(rm[r], sv);
      }
    }
#pragma unroll
    for (int r = 0; r < 4; ++r) {
#pragma unroll
      for (int m = 1; m < 16; m <<= 1) rm[r] = fmaxf(rm[r], __shfl_xor(rm[r], m, 64));
      float mn = fmaxf(mrun[r], rm[r]);
      float corr = __expf(mrun[r] - mn);
      mrun[r] = mn;
      lrun[r] *= corr;
#pragma unroll
      for (int f = 0; f < 8; ++f) oacc[f][r] *= corr;
    }
    float rs[4] = {0.f, 0.f, 0.f, 0.f};
#pragma unroll
    for (int n = 0; n < 4; ++n)
#pragma unroll
      for (int r = 0; r < 4; ++r) {
        float e = __expf(pv[n][r] - mrun[r]);
        pv[n][r] = e;
        rs[r] += e;
      }
#pragma unroll
    for (int r = 0; r < 4; ++r) {
#pragma unroll
      for (int m = 1; m < 16; m <<= 1) rs[r] += __shfl_xor(rs[r], m, 64);
      lrun[r] += rs[r];
    }

    // P (C-layout) -> LDS (swizzled) -> reload in A-layout (wave-local)
#pragma unroll
    for (int n = 0; n < 4; ++n)
#pragma unroll
      for (int r = 0; r < 4; ++r) {
        int row = lq * 4 + r;
        int chsw = (n * 2 + (la >> 3)) ^ (row & 7);
        Ps[w][row * 64 + chsw * 8 + (la & 7)] = (_Float16)pv[n][r];
      }
    asm volatile("s_waitcnt lgkmcnt(0)" ::: "memory");
    __builtin_amdgcn_sched_barrier(0);
    h8 pf[2];
#pragma unroll
    for (int ks = 0; ks < 2; ++ks)
      pf[ks] = *(const h8*)&Ps[w][la * 64 + (((ks * 4 + lq) ^ (la & 7)) * 8)];

    // PV: oacc[16 rows][128 d]
    __builtin_amdgcn_s_setprio(1);
#pragma unroll
    for (int f = 0; f < 8; ++f) {
      int row = f * 16 + la;
#pragma unroll
      for (int ks = 0; ks < 2; ++ks) {
        h8 bv = *(const h8*)&Vs[cur][row * 64 + (((ks * 4 + lq) ^ (la & 7)) * 8)];
        oacc[f] = __builtin_amdgcn_mfma_f32_16x16x32_f16(pf[ks], bv, oacc[f], 0, 0, 0);
      }
    }
    __builtin_amdgcn_s_setprio(0);

    if (maskT) {  // last tile of this q-tile: write output
      _Float16* Cg = ctx + ((size_t)(b * NS + qrow0)) * ND + h * NHD + la;
      float inv_l[4];
#pragma unroll
      for (int r = 0; r < 4; ++r) inv_l[r] = 1.0f / lrun[r];
#pragma unroll
      for (int f = 0; f < 8; ++f)
#pragma unroll
        for (int r = 0; r < 4; ++r)
          Cg[(size_t)r * ND + f * 16] = (_Float16)(oacc[f][r] * inv_l[r]);
    }
    cur ^= 1;
  }
}

// ---------------- launch ----------------

extern "C" void kernel_launch(void* const* d_in, const int* in_sizes, int n_in,
                              void* d_out, int out_size, void* d_ws, size_t ws_size,
                              hipStream_t stream) {
  (void)in_sizes; (void)n_in; (void)out_size; (void)ws_size;
  const float* x = (const float*)d_in[0];
  const float* wq = (const float*)d_in[1];
  const float* bq = (const float*)d_in[2];
  const float* wk = (const float*)d_in[3];
  const float* bk = (const float*)d_in[4];
  const float* wv = (const float*)d_in[5];
  const float* bv = (const float*)d_in[6];
  const float* wo = (const float*)d_in[7];
  const float* bo = (const float*)d_in[8];
  const float* qns = (const float*)d_in[9];
  const float* kns = (const float*)d_in[10];

  char* ws = (char*)d_ws;
  size_t off = 0;
  _Float16* xh = (_Float16*)(ws + off); off += (size_t)NM * ND * 2;       // 32MB
  _Float16* wqt = (_Float16*)(ws + off); off += (size_t)ND * ND * 2;      // 8MB
  _Float16* wkvt = (_Float16*)(ws + off); off += (size_t)NKV * ND * 2;    // 4MB
  _Float16* wot = (_Float16*)(ws + off); off += (size_t)ND * ND * 2;      // 8MB
  _Float16* Qb = (_Float16*)(ws + off); off += (size_t)NM * ND * 2;       // 32MB
  _Float16* KVbuf = (_Float16*)(ws + off); off += (size_t)NM * NKV * 2;   // 16MB
  float* cosT = (float*)(ws + off); off += (size_t)NS * 64 * 4;
  float* sinT = (float*)(ws + off); off += (size_t)NS * 64 * 4;
  float* bkv = (float*)(ws + off); off += (size_t)NKV * 4;
  _Float16* ctx = xh;            // xh dead after KV GEMM; reuse
  _Float16* Vtg = wqt;           // wqt dead after Q GEMM; reuse (needs 8MB)

  cvt_x_kernel<<<NM * ND / 8 / 256, 256, 0, stream>>>(x, xh, NM * ND / 8);
  wtrans_kernel<<<dim3(ND / 64, ND / 64), 256, 0, stream>>>(wq, wqt, ND, ND);
  wtrans_kernel<<<dim3(NKD / 64, ND / 64), 256, 0, stream>>>(wk, wkvt, ND, NKD);
  wtrans_kernel<<<dim3(NKD / 64, ND / 64), 256, 0, stream>>>(wv, wkvt + (size_t)NKD * ND, ND, NKD);
  wtrans_kernel<<<dim3(ND / 64, ND / 64), 256, 0, stream>>>(wo, wot, ND, ND);
  rope_tables_kernel<<<NS * 64 / 256, 256, 0, stream>>>(cosT, sinT);
  hipMemcpyAsync(bkv, bk, NKD * sizeof(float), hipMemcpyDeviceToDevice, stream);
  hipMemcpyAsync(bkv + NKD, bv, NKD * sizeof(float), hipMemcpyDeviceToDevice, stream);

  gemm256_kernel<_Float16><<<dim3(256), dim3(512), 0, stream>>>(xh, wqt, bq, Qb, ND, ND);
  gemm_bt_kernel<_Float16><<<dim3(NKV / 128, NM / 128), 256, 0, stream>>>(xh, wkvt, bkv, KVbuf, NKV, ND);

  norm_rope_kernel<<<NM * NH / 4, 256, 0, stream>>>(Qb, qns, cosT, sinT, 4, ND, HEAD_SCALE);
  norm_rope_kernel<<<NM * NG / 4, 256, 0, stream>>>(KVbuf, kns, cosT, sinT, 2, NKV, 1.0f);

  vtrans_kernel<<<dim3(NS / 64, NHD / 64, NB * NG), 256, 0, stream>>>(KVbuf, Vtg);

  attn_kernel<<<dim3(512), dim3(512), 0, stream>>>(Qb, KVbuf, Vtg, ctx);

  gemm256_kernel<float><<<dim3(256), dim3(512), 0, stream>>>(ctx, wot, bo, (float*)d_out, ND, ND);
}